// Round 3
// baseline (1183.041 us; speedup 1.0000x reference)
//
#include <hip/hip_runtime.h>
#include <cstdint>
#include <cstddef>

#define NN 50000
#define EE 800000
#define FIN 32
#define EDD 10
#define GG 512
#define CC 64
static constexpr float EPSV = 1e-5f;

__device__ __forceinline__ float lrelu(float x, float s) { return x > 0.f ? x : s * x; }

// ---------------- preprocessing ----------------
__global__ void k_count(const int* __restrict__ dst, int* __restrict__ deg) {
  int e = blockIdx.x * blockDim.x + threadIdx.x;
  if (e < EE) atomicAdd(&deg[dst[e]], 1);
}

__global__ void k_gcnt(const int* __restrict__ batch, float* __restrict__ gcnt) {
  int n = blockIdx.x * blockDim.x + threadIdx.x;
  if (n < NN) atomicAdd(&gcnt[batch[n]], 1.f);
}

// single-block exclusive scan of deg[NN] -> row_off[NN+1]
__global__ void k_scan(const int* __restrict__ deg, int* __restrict__ row_off) {
  __shared__ int sm[1024];
  int tid = threadIdx.x;
  constexpr int CPT = (NN + 1023) / 1024;  // 49
  int b = tid * CPT;
  int local[CPT];
  int s = 0;
#pragma unroll
  for (int j = 0; j < CPT; ++j) {
    int i = b + j;
    int v = (i < NN) ? deg[i] : 0;
    local[j] = s;
    s += v;
  }
  sm[tid] = s;
  __syncthreads();
  for (int off = 1; off < 1024; off <<= 1) {
    int t = (tid >= off) ? sm[tid - off] : 0;
    __syncthreads();
    sm[tid] += t;
    __syncthreads();
  }
  int base = (tid > 0) ? sm[tid - 1] : 0;
#pragma unroll
  for (int j = 0; j < CPT; ++j) {
    int i = b + j;
    if (i < NN) row_off[i] = base + local[j];
  }
  if (tid == 1023) row_off[NN] = sm[1023];
}

__global__ void k_fill(const int* __restrict__ src, const int* __restrict__ dst,
                       const int* __restrict__ row_off, int* __restrict__ cursor,
                       int* __restrict__ perm, int* __restrict__ src_sorted,
                       int* __restrict__ dst_sorted) {
  int e = blockIdx.x * blockDim.x + threadIdx.x;
  if (e >= EE) return;
  int d = dst[e];
  int pos = row_off[d] + atomicAdd(&cursor[d], 1);
  perm[pos] = e;
  src_sorted[pos] = src[e];
  dst_sorted[pos] = d;
}

// loop_ea[n][:] = mean of incoming ea rows (0 if deg==0). One wave per node.
__global__ void k_loop_ea(const float* __restrict__ ea, const int* __restrict__ perm,
                          const int* __restrict__ row_off, float* __restrict__ loop_ea) {
  int wid = threadIdx.x >> 6, lane = threadIdx.x & 63;
  int n = blockIdx.x * 4 + wid;
  if (n >= NN) return;
  int beg = row_off[n], end = row_off[n + 1];
  float s[EDD];
#pragma unroll
  for (int d = 0; d < EDD; ++d) s[d] = 0.f;
  for (int i = beg + lane; i < end; i += 64) {
    const float* r = ea + (size_t)perm[i] * EDD;
#pragma unroll
    for (int d = 0; d < EDD; ++d) s[d] += r[d];
  }
#pragma unroll
  for (int off = 32; off > 0; off >>= 1)
#pragma unroll
    for (int d = 0; d < EDD; ++d) s[d] += __shfl_xor(s[d], off);
  if (lane == 0) {
    float inv = 1.f / (float)max(end - beg, 1);
#pragma unroll
    for (int d = 0; d < EDD; ++d) loop_ea[n * EDD + d] = s[d] * inv;
  }
}

// was[k*H+h] = sum_c W[k,h*C+c]*as[h,c]; wad likewise; weae[d*H+h] = sum_c We[d,h*C+c]*ae[h,c]
template <int H, int K>
__global__ void k_prep(const float* __restrict__ W, const float* __restrict__ as_,
                       const float* __restrict__ ad_, const float* __restrict__ We,
                       const float* __restrict__ ae, float* __restrict__ was,
                       float* __restrict__ wad, float* __restrict__ weae) {
  int t = threadIdx.x;
  if (t < K * H) {
    int k = t / H, h = t % H;
    float s = 0.f;
    for (int c = 0; c < CC; ++c) s += W[(size_t)k * (H * CC) + h * CC + c] * as_[h * CC + c];
    was[t] = s;
  } else if (t < 2 * K * H) {
    int u = t - K * H;
    int k = u / H, h = u % H;
    float s = 0.f;
    for (int c = 0; c < CC; ++c) s += W[(size_t)k * (H * CC) + h * CC + c] * ad_[h * CC + c];
    wad[u] = s;
  } else if (t < 2 * K * H + EDD * H) {
    int u = t - 2 * K * H;
    int d = u / H, h = u % H;
    float s = 0.f;
    for (int c = 0; c < CC; ++c) s += We[(size_t)d * (H * CC) + h * CC + c] * ae[h * CC + c];
    weae[u] = s;
  }
}

// xw = in[N,K] @ W[K,M], plus asrc/adst epilogue from the LDS tile.
template <int K, int M, int H>
__global__ void k_gemm(const float* __restrict__ in, const float* __restrict__ W,
                       const float* __restrict__ was, const float* __restrict__ wad,
                       float* __restrict__ xw, float* __restrict__ asrc,
                       float* __restrict__ adst) {
  constexpr int BR = 32;
  constexpr int CG = M / 4;     // col groups of 4
  constexpr int RG = 256 / CG;  // row groups
  constexpr int R = BR / RG;    // rows per thread
  __shared__ float4 xs4[BR][K / 4];
  int tid = threadIdx.x;
  int rbase = blockIdx.x * BR;
  for (int j = tid; j < BR * K / 4; j += 256) {
    int row = j / (K / 4), kq = j % (K / 4);
    int gr = rbase + row;
    float4 v = {0.f, 0.f, 0.f, 0.f};
    if (gr < NN) v = *(const float4*)(in + (size_t)gr * K + kq * 4);
    xs4[row][kq] = v;
  }
  __syncthreads();
  int cg = tid % CG, rg = tid / CG;
  int col0 = cg * 4;
  float acc[R][4];
#pragma unroll
  for (int r = 0; r < R; ++r)
#pragma unroll
    for (int c = 0; c < 4; ++c) acc[r][c] = 0.f;
  for (int k0 = 0; k0 < K; k0 += 4) {
    float4 wv[4];
#pragma unroll
    for (int kk = 0; kk < 4; ++kk) wv[kk] = *(const float4*)(W + (size_t)(k0 + kk) * M + col0);
#pragma unroll
    for (int r = 0; r < R; ++r) {
      float4 xv = xs4[rg * R + r][k0 / 4];
      const float* xf = (const float*)&xv;
#pragma unroll
      for (int kk = 0; kk < 4; ++kk) {
        const float* wf = (const float*)&wv[kk];
        float xk = xf[kk];
#pragma unroll
        for (int c = 0; c < 4; ++c) acc[r][c] += xk * wf[c];
      }
    }
  }
#pragma unroll
  for (int r = 0; r < R; ++r) {
    int gr = rbase + rg * R + r;
    if (gr < NN) {
      float4 v;
      v.x = acc[r][0]; v.y = acc[r][1]; v.z = acc[r][2]; v.w = acc[r][3];
      *(float4*)(xw + (size_t)gr * M + col0) = v;
    }
  }
  // epilogue: asrc/adst for this row tile
  if (tid < 2 * BR * H) {
    int which = tid / (BR * H);
    int u = tid % (BR * H);
    int row = u / H, h = u % H;
    int gr = rbase + row;
    if (gr < NN) {
      const float* wv = which ? wad : was;
      const float* xr = (const float*)&xs4[row][0];
      float s = 0.f;
      for (int k = 0; k < K; ++k) s += xr[k] * wv[k * H + h];
      (which ? adst : asrc)[(size_t)gr * H + h] = s;
    }
  }
}

// logits in dst-sorted order (+ self-loop logits)
template <int H>
__global__ void k_edge(const float* __restrict__ ea, const float* __restrict__ loop_ea,
                       const float* __restrict__ weae, const int* __restrict__ perm,
                       const int* __restrict__ src_sorted, const int* __restrict__ dst_sorted,
                       const float* __restrict__ asrc, const float* __restrict__ adst,
                       float* __restrict__ logit, float* __restrict__ logit_loop) {
  __shared__ float wsm[EDD * H];
  if (threadIdx.x < EDD * H) wsm[threadIdx.x] = weae[threadIdx.x];
  __syncthreads();
  int idx = blockIdx.x * blockDim.x + threadIdx.x;
  const float* row;
  int s, d;
  float* outp;
  if (idx < EE) {
    int e = perm[idx];
    row = ea + (size_t)e * EDD;
    s = src_sorted[idx];
    d = dst_sorted[idx];
    outp = logit + (size_t)idx * H;
  } else if (idx < EE + NN) {
    int n = idx - EE;
    row = loop_ea + (size_t)n * EDD;
    s = n; d = n;
    outp = logit_loop + (size_t)n * H;
  } else
    return;
  float r[EDD];
#pragma unroll
  for (int dd = 0; dd < EDD; ++dd) r[dd] = row[dd];
#pragma unroll
  for (int h = 0; h < H; ++h) {
    float ae = 0.f;
#pragma unroll
    for (int dd = 0; dd < EDD; ++dd) ae += r[dd] * wsm[dd * H + h];
    outp[h] = lrelu(asrc[(size_t)s * H + h] + adst[(size_t)d * H + h] + ae, 0.2f);
  }
}

// fused GAT node kernel: one wave per node; float4 multi-edge gather of xw.
template <int H>
__global__ void k_node(const float* __restrict__ xw, const float* __restrict__ logit,
                       const float* __restrict__ logit_loop, const int* __restrict__ row_off,
                       const int* __restrict__ src_sorted, const float* __restrict__ bias,
                       float* __restrict__ out) {
  constexpr int RW4 = H * CC / 4;  // float4s per xw row
  int wid = threadIdx.x >> 6, lane = threadIdx.x & 63;
  int n = blockIdx.x * 4 + wid;
  if (n >= NN) return;
  int beg = row_off[n], end = row_off[n + 1];
  float sl[H], m[H];
#pragma unroll
  for (int h = 0; h < H; ++h) {
    sl[h] = logit_loop[(size_t)n * H + h];
    m[h] = sl[h];
  }
  // pass 1: max
  for (int i = beg + lane; i < end; i += 64) {
    const float* lv = logit + (size_t)i * H;
#pragma unroll
    for (int h = 0; h < H; ++h) m[h] = fmaxf(m[h], lv[h]);
  }
#pragma unroll
  for (int off = 32; off > 0; off >>= 1)
#pragma unroll
    for (int h = 0; h < H; ++h) m[h] = fmaxf(m[h], __shfl_xor(m[h], off));
  // pass 2: denom
  float dp[H];
#pragma unroll
  for (int h = 0; h < H; ++h) dp[h] = 0.f;
  for (int i = beg + lane; i < end; i += 64) {
    const float* lv = logit + (size_t)i * H;
#pragma unroll
    for (int h = 0; h < H; ++h) dp[h] += __expf(lv[h] - m[h]);
  }
#pragma unroll
  for (int off = 32; off > 0; off >>= 1)
#pragma unroll
    for (int h = 0; h < H; ++h) dp[h] += __shfl_xor(dp[h], off);
  float inv[H], asf[H];
#pragma unroll
  for (int h = 0; h < H; ++h) {
    float ps = __expf(sl[h] - m[h]);
    float den = dp[h] + ps;
    inv[h] = 1.f / den;
    asf[h] = ps * inv[h];
  }
  // pass 3: aggregation, alpha pre-multiplied
  const float4* xw4 = (const float4*)xw;
  float4 accA = {0.f, 0.f, 0.f, 0.f};
  float4 accB = {0.f, 0.f, 0.f, 0.f};
  for (int cb = beg; cb < end; cb += 64) {
    int i = cb + lane;
    float a[H];
    int s = 0;
    if (i < end) {
      const float* lv = logit + (size_t)i * H;
#pragma unroll
      for (int h = 0; h < H; ++h) a[h] = __expf(lv[h] - m[h]) * inv[h];
      s = src_sorted[i];
    } else {
#pragma unroll
      for (int h = 0; h < H; ++h) a[h] = 0.f;
    }
    int cnt = min(64, end - cb);
    if (H == 4) {
      int sub = lane >> 4, g = lane & 15;
      for (int j = 0; j < cnt; j += 4) {
        int jj = j + sub;
        bool valid = jj < cnt;
        int sj = __shfl(s, valid ? jj : 0);
        size_t rb = (size_t)sj * RW4 + g;
#pragma unroll
        for (int q = 0; q < 4; ++q) {
          float pj = __shfl(a[q], jj);
          pj = valid ? pj : 0.f;
          float4 v = xw4[rb + 16 * q];
          accA.x += pj * v.x; accA.y += pj * v.y; accA.z += pj * v.z; accA.w += pj * v.w;
        }
      }
    } else {
      int sub = lane >> 3, g = lane & 7;
      for (int j = 0; j < cnt; j += 8) {
        int jj = j + sub;
        bool valid = jj < cnt;
        int sj = __shfl(s, valid ? jj : 0);
        size_t rb = (size_t)sj * RW4 + g;
#pragma unroll
        for (int q = 0; q < 4; ++q) {
          float pj = __shfl(a[q >> 1], jj);
          pj = valid ? pj : 0.f;
          float4 v = xw4[rb + 8 * q];
          if (q & 1) {
            accB.x += pj * v.x; accB.y += pj * v.y; accB.z += pj * v.z; accB.w += pj * v.w;
          } else {
            accA.x += pj * v.x; accA.y += pj * v.y; accA.z += pj * v.z; accA.w += pj * v.w;
          }
        }
      }
    }
  }
  // self term (ONCE: only sub==0 lane group, since acc is reduced over subs) + reduce + store
  if (H == 4) {
    int g = lane & 15, sub = lane >> 4;
    if (sub == 0) {
      size_t rb = (size_t)n * RW4 + g;
#pragma unroll
      for (int q = 0; q < 4; ++q) {
        float4 v = xw4[rb + 16 * q];
        accA.x += asf[q] * v.x; accA.y += asf[q] * v.y; accA.z += asf[q] * v.z; accA.w += asf[q] * v.w;
      }
    }
#pragma unroll
    for (int off = 16; off < 64; off <<= 1) {
      accA.x += __shfl_xor(accA.x, off);
      accA.y += __shfl_xor(accA.y, off);
      accA.z += __shfl_xor(accA.z, off);
      accA.w += __shfl_xor(accA.w, off);
    }
    if (lane < 16) {
      float4 b4 = *(const float4*)(bias + 4 * g);
      float4 res;
      res.x = accA.x * 0.25f + b4.x;
      res.y = accA.y * 0.25f + b4.y;
      res.z = accA.z * 0.25f + b4.z;
      res.w = accA.w * 0.25f + b4.w;
      *(float4*)(out + (size_t)n * CC + 4 * g) = res;
    }
  } else {
    int g = lane & 7, sub = lane >> 3;
    if (sub == 0) {
      size_t rb = (size_t)n * RW4 + g;
#pragma unroll
      for (int q = 0; q < 4; ++q) {
        float4 v = xw4[rb + 8 * q];
        float as_ = asf[q >> 1];
        if (q & 1) {
          accB.x += as_ * v.x; accB.y += as_ * v.y; accB.z += as_ * v.z; accB.w += as_ * v.w;
        } else {
          accA.x += as_ * v.x; accA.y += as_ * v.y; accA.z += as_ * v.z; accA.w += as_ * v.w;
        }
      }
    }
#pragma unroll
    for (int off = 8; off < 64; off <<= 1) {
      accA.x += __shfl_xor(accA.x, off);
      accA.y += __shfl_xor(accA.y, off);
      accA.z += __shfl_xor(accA.z, off);
      accA.w += __shfl_xor(accA.w, off);
      accB.x += __shfl_xor(accB.x, off);
      accB.y += __shfl_xor(accB.y, off);
      accB.z += __shfl_xor(accB.z, off);
      accB.w += __shfl_xor(accB.w, off);
    }
    if (lane < 16) {
      int g2 = lane & 7;
      int c = (lane < 8) ? 4 * g2 : 32 + 4 * g2;
      float4 sv = (lane < 8) ? accA : accB;
      float4 b4 = *(const float4*)(bias + c);
      float4 res;
      res.x = sv.x * 0.5f + b4.x;
      res.y = sv.y * 0.5f + b4.y;
      res.z = sv.z * 0.5f + b4.z;
      res.w = sv.w * 0.5f + b4.w;
      *(float4*)(out + (size_t)n * CC + c) = res;
    }
  }
}

// ---------------- BatchNorm ----------------
__global__ void k_bn_partial(const float* __restrict__ x, float* __restrict__ psum,
                             float* __restrict__ psum2, int rows_per_block) {
  int c = threadIdx.x & 63;
  int rsub = threadIdx.x >> 6;
  int r0 = blockIdx.x * rows_per_block;
  int r1 = min(r0 + rows_per_block, NN);
  float s = 0.f, s2 = 0.f;
  for (int r = r0 + rsub; r < r1; r += 4) {
    float v = x[(size_t)r * CC + c];
    s += v;
    s2 += v * v;
  }
  __shared__ float sm[256], sm2[256];
  sm[threadIdx.x] = s;
  sm2[threadIdx.x] = s2;
  __syncthreads();
  if (rsub == 0) {
    s = sm[c] + sm[64 + c] + sm[128 + c] + sm[192 + c];
    s2 = sm2[c] + sm2[64 + c] + sm2[128 + c] + sm2[192 + c];
    psum[blockIdx.x * CC + c] = s;
    psum2[blockIdx.x * CC + c] = s2;
  }
}

__global__ void k_bn_final(const float* __restrict__ psum, const float* __restrict__ psum2,
                           const float* __restrict__ g, const float* __restrict__ be,
                           float* __restrict__ scale, float* __restrict__ shift, int nblk) {
  int c = threadIdx.x;
  if (c >= CC) return;
  float s = 0.f, s2 = 0.f;
  for (int b = 0; b < nblk; ++b) {
    s += psum[b * CC + c];
    s2 += psum2[b * CC + c];
  }
  float mu = s / (float)NN;
  float var = s2 / (float)NN - mu * mu;
  float sc = g[c] * rsqrtf(var + EPSV);
  scale[c] = sc;
  shift[c] = be[c] - mu * sc;
}

__global__ void k_bn_apply(float* __restrict__ x, const float* __restrict__ scale,
                           const float* __restrict__ shift, float slope) {
  int i = blockIdx.x * blockDim.x + threadIdx.x;
  if (i >= NN * CC) return;
  int c = i & 63;
  float v = x[i] * scale[c] + shift[c];
  x[i] = lrelu(v, slope);
}

// final layer: BN + leaky_relu + pooled atomicAdd (no write-back needed)
__global__ void k_bn_apply_pool(const float* __restrict__ x, const float* __restrict__ scale,
                                const float* __restrict__ shift, const int* __restrict__ batch,
                                float* __restrict__ pooled) {
  int i = blockIdx.x * blockDim.x + threadIdx.x;
  if (i >= NN * CC) return;
  int nidx = i >> 6, c = i & 63;
  float v = x[i] * scale[c] + shift[c];
  v = lrelu(v, 0.01f);
  atomicAdd(&pooled[batch[nidx] * CC + c], v);
}

__global__ void k_head(const float* __restrict__ pooled, const float* __restrict__ gcnt,
                       const float* __restrict__ fw1, const float* __restrict__ fb1,
                       const float* __restrict__ fw2, const float* __restrict__ fb2,
                       float* __restrict__ out) {
  int g = blockIdx.x;
  int j = threadIdx.x;  // 64
  float inv = 1.f / fmaxf(gcnt[g], 1.f);
  float h1 = fb1[j];
  for (int k = 0; k < CC; ++k) h1 += (pooled[g * CC + k] * inv) * fw1[k * CC + j];
  h1 = fmaxf(h1, 0.f);
  float o = h1 * fw2[j];
#pragma unroll
  for (int off = 32; off > 0; off >>= 1) o += __shfl_xor(o, off);
  if (j == 0) out[g] = o + fb2[0];
}

// ---------------- launch ----------------
extern "C" void kernel_launch(void* const* d_in, const int* in_sizes, int n_in,
                              void* d_out, int out_size, void* d_ws, size_t ws_size,
                              hipStream_t stream) {
  const float* x = (const float*)d_in[0];
  const int* eidx = (const int*)d_in[1];
  const float* ea = (const float*)d_in[2];
  const int* batch = (const int*)d_in[3];
  const float* w[3] = {(const float*)d_in[4], (const float*)d_in[12], (const float*)d_in[20]};
  const float* as_[3] = {(const float*)d_in[5], (const float*)d_in[13], (const float*)d_in[21]};
  const float* ad_[3] = {(const float*)d_in[6], (const float*)d_in[14], (const float*)d_in[22]};
  const float* we_[3] = {(const float*)d_in[7], (const float*)d_in[15], (const float*)d_in[23]};
  const float* ae_[3] = {(const float*)d_in[8], (const float*)d_in[16], (const float*)d_in[24]};
  const float* b_[3] = {(const float*)d_in[9], (const float*)d_in[17], (const float*)d_in[25]};
  const float* g_[3] = {(const float*)d_in[10], (const float*)d_in[18], (const float*)d_in[26]};
  const float* be_[3] = {(const float*)d_in[11], (const float*)d_in[19], (const float*)d_in[27]};
  const float* fw1 = (const float*)d_in[28];
  const float* fb1 = (const float*)d_in[29];
  const float* fw2 = (const float*)d_in[30];
  const float* fb2 = (const float*)d_in[31];
  const int* srcp = eidx;
  const int* dstp = eidx + EE;

  char* base = (char*)d_ws;
  size_t off = 0;
  auto alloc = [&](size_t bytes) {
    void* p = base + off;
    off = (off + bytes + 255) & ~(size_t)255;
    return p;
  };
  int* deg_i = (int*)alloc((size_t)NN * 4);
  int* row_off = (int*)alloc((size_t)(NN + 1) * 4);
  int* cursor = (int*)alloc((size_t)NN * 4);
  int* perm = (int*)alloc((size_t)EE * 4);
  int* src_sorted = (int*)alloc((size_t)EE * 4);
  int* dst_sorted = (int*)alloc((size_t)EE * 4);
  float* loop_ea = (float*)alloc((size_t)NN * EDD * 4);
  float* logit = (float*)alloc((size_t)EE * 4 * 4);
  float* logit_loop = (float*)alloc((size_t)NN * 4 * 4);
  float* asrc = (float*)alloc((size_t)NN * 4 * 4);
  float* adst = (float*)alloc((size_t)NN * 4 * 4);
  float* xw = (float*)alloc((size_t)NN * 256 * 4);
  float* h0 = (float*)alloc((size_t)NN * CC * 4);
  float* h1 = (float*)alloc((size_t)NN * CC * 4);
  float* psum = (float*)alloc((size_t)128 * CC * 4);
  float* psum2 = (float*)alloc((size_t)128 * CC * 4);
  float* bnscale = (float*)alloc(CC * 4);
  float* bnshift = (float*)alloc(CC * 4);
  float* weae = (float*)alloc(EDD * 4 * 4);
  float* was = (float*)alloc((size_t)CC * 4 * 4);
  float* wad = (float*)alloc((size_t)CC * 4 * 4);
  float* pooled = (float*)alloc((size_t)GG * CC * 4);
  float* gcnt = (float*)alloc((size_t)GG * 4);
  (void)ws_size; (void)in_sizes; (void)n_in; (void)out_size;

  hipMemsetAsync(deg_i, 0, (size_t)NN * 4, stream);
  hipMemsetAsync(cursor, 0, (size_t)NN * 4, stream);
  hipMemsetAsync(pooled, 0, (size_t)GG * CC * 4, stream);
  hipMemsetAsync(gcnt, 0, (size_t)GG * 4, stream);

  k_count<<<(EE + 255) / 256, 256, 0, stream>>>(dstp, deg_i);
  k_gcnt<<<(NN + 255) / 256, 256, 0, stream>>>(batch, gcnt);
  k_scan<<<1, 1024, 0, stream>>>(deg_i, row_off);
  k_fill<<<(EE + 255) / 256, 256, 0, stream>>>(srcp, dstp, row_off, cursor, perm, src_sorted,
                                               dst_sorted);
  k_loop_ea<<<(NN + 3) / 4, 256, 0, stream>>>(ea, perm, row_off, loop_ea);

  for (int l = 0; l < 3; ++l) {
    const float* in = (l == 0) ? x : ((l == 1) ? h0 : h1);
    float* outb = (l == 0) ? h0 : ((l == 1) ? h1 : h0);
    if (l == 0) {
      k_prep<4, FIN><<<1, 1024, 0, stream>>>(w[l], as_[l], ad_[l], we_[l], ae_[l], was, wad, weae);
      k_gemm<FIN, 256, 4><<<(NN + 31) / 32, 256, 0, stream>>>(in, w[l], was, wad, xw, asrc, adst);
      k_edge<4><<<(EE + NN + 255) / 256, 256, 0, stream>>>(ea, loop_ea, weae, perm, src_sorted,
                                                           dst_sorted, asrc, adst, logit, logit_loop);
      k_node<4><<<(NN + 3) / 4, 256, 0, stream>>>(xw, logit, logit_loop, row_off, src_sorted,
                                                  b_[l], outb);
    } else if (l == 1) {
      k_prep<2, CC><<<1, 1024, 0, stream>>>(w[l], as_[l], ad_[l], we_[l], ae_[l], was, wad, weae);
      k_gemm<CC, 128, 2><<<(NN + 31) / 32, 256, 0, stream>>>(in, w[l], was, wad, xw, asrc, adst);
      k_edge<2><<<(EE + NN + 255) / 256, 256, 0, stream>>>(ea, loop_ea, weae, perm, src_sorted,
                                                           dst_sorted, asrc, adst, logit, logit_loop);
      k_node<2><<<(NN + 3) / 4, 256, 0, stream>>>(xw, logit, logit_loop, row_off, src_sorted,
                                                  b_[l], outb);
    } else {
      k_prep<4, CC><<<1, 1024, 0, stream>>>(w[l], as_[l], ad_[l], we_[l], ae_[l], was, wad, weae);
      k_gemm<CC, 256, 4><<<(NN + 31) / 32, 256, 0, stream>>>(in, w[l], was, wad, xw, asrc, adst);
      k_edge<4><<<(EE + NN + 255) / 256, 256, 0, stream>>>(ea, loop_ea, weae, perm, src_sorted,
                                                           dst_sorted, asrc, adst, logit, logit_loop);
      k_node<4><<<(NN + 3) / 4, 256, 0, stream>>>(xw, logit, logit_loop, row_off, src_sorted,
                                                  b_[l], outb);
    }

    int rpb = (NN + 127) / 128;
    k_bn_partial<<<128, 256, 0, stream>>>(outb, psum, psum2, rpb);
    k_bn_final<<<1, 64, 0, stream>>>(psum, psum2, g_[l], be_[l], bnscale, bnshift, 128);
    if (l < 2)
      k_bn_apply<<<(NN * CC + 255) / 256, 256, 0, stream>>>(outb, bnscale, bnshift, 0.0f);
    else
      k_bn_apply_pool<<<(NN * CC + 255) / 256, 256, 0, stream>>>(outb, bnscale, bnshift, batch,
                                                                 pooled);
  }

  k_head<<<GG, 64, 0, stream>>>(pooled, gcnt, fw1, fb1, fw2, fb2, (float*)d_out);
}

// Round 4
// 916.133 us; speedup vs baseline: 1.2913x; 1.2913x over previous
//
#include <hip/hip_runtime.h>
#include <cstdint>
#include <cstddef>

#define NN 50000
#define EE 800000
#define FIN 32
#define EDD 10
#define GG 512
#define CC 64
static constexpr float EPSV = 1e-5f;

__device__ __forceinline__ float lrelu(float x, float s) { return x > 0.f ? x : s * x; }

// ---------------- preprocessing ----------------
__global__ __launch_bounds__(256) void k_count(const int* __restrict__ dst, int* __restrict__ deg) {
  int e = blockIdx.x * blockDim.x + threadIdx.x;
  if (e < EE) atomicAdd(&deg[dst[e]], 1);
}

__global__ __launch_bounds__(256) void k_gcnt(const int* __restrict__ batch, float* __restrict__ gcnt) {
  int n = blockIdx.x * blockDim.x + threadIdx.x;
  if (n < NN) atomicAdd(&gcnt[batch[n]], 1.f);
}

// single-block exclusive scan of deg[NN] -> row_off[NN+1]
__global__ __launch_bounds__(1024) void k_scan(const int* __restrict__ deg, int* __restrict__ row_off) {
  __shared__ int sm[1024];
  int tid = threadIdx.x;
  constexpr int CPT = (NN + 1023) / 1024;  // 49
  int b = tid * CPT;
  int local[CPT];
  int s = 0;
#pragma unroll
  for (int j = 0; j < CPT; ++j) {
    int i = b + j;
    int v = (i < NN) ? deg[i] : 0;
    local[j] = s;
    s += v;
  }
  sm[tid] = s;
  __syncthreads();
  for (int off = 1; off < 1024; off <<= 1) {
    int t = (tid >= off) ? sm[tid - off] : 0;
    __syncthreads();
    sm[tid] += t;
    __syncthreads();
  }
  int base = (tid > 0) ? sm[tid - 1] : 0;
#pragma unroll
  for (int j = 0; j < CPT; ++j) {
    int i = b + j;
    if (i < NN) row_off[i] = base + local[j];
  }
  if (tid == 1023) row_off[NN] = sm[1023];
}

__global__ __launch_bounds__(256) void k_fill(const int* __restrict__ src, const int* __restrict__ dst,
                       const int* __restrict__ row_off, int* __restrict__ cursor,
                       int* __restrict__ perm, int* __restrict__ src_sorted,
                       int* __restrict__ dst_sorted) {
  int e = blockIdx.x * blockDim.x + threadIdx.x;
  if (e >= EE) return;
  int d = dst[e];
  int pos = row_off[d] + atomicAdd(&cursor[d], 1);
  perm[pos] = e;
  src_sorted[pos] = src[e];
  dst_sorted[pos] = d;
}

// loop_ea[n][:] = mean of incoming ea rows (0 if deg==0). One wave per node.
__global__ __launch_bounds__(256) void k_loop_ea(const float* __restrict__ ea, const int* __restrict__ perm,
                          const int* __restrict__ row_off, float* __restrict__ loop_ea) {
  int wid = threadIdx.x >> 6, lane = threadIdx.x & 63;
  int n = blockIdx.x * 4 + wid;
  if (n >= NN) return;
  int beg = row_off[n], end = row_off[n + 1];
  float s[EDD];
#pragma unroll
  for (int d = 0; d < EDD; ++d) s[d] = 0.f;
  for (int i = beg + lane; i < end; i += 64) {
    const float* r = ea + (size_t)perm[i] * EDD;
#pragma unroll
    for (int d = 0; d < EDD; ++d) s[d] += r[d];
  }
#pragma unroll
  for (int off = 32; off > 0; off >>= 1)
#pragma unroll
    for (int d = 0; d < EDD; ++d) s[d] += __shfl_xor(s[d], off);
  if (lane == 0) {
    float inv = 1.f / (float)max(end - beg, 1);
#pragma unroll
    for (int d = 0; d < EDD; ++d) loop_ea[n * EDD + d] = s[d] * inv;
  }
}

// was[k*H+h] = sum_c W[k,h*C+c]*as[h,c]; wad likewise; weae[d*H+h] = sum_c We[d,h*C+c]*ae[h,c]
template <int H, int K>
__global__ __launch_bounds__(1024) void k_prep(const float* __restrict__ W, const float* __restrict__ as_,
                       const float* __restrict__ ad_, const float* __restrict__ We,
                       const float* __restrict__ ae, float* __restrict__ was,
                       float* __restrict__ wad, float* __restrict__ weae) {
  int t = threadIdx.x;
  if (t < K * H) {
    int k = t / H, h = t % H;
    float s = 0.f;
    for (int c = 0; c < CC; ++c) s += W[(size_t)k * (H * CC) + h * CC + c] * as_[h * CC + c];
    was[t] = s;
  } else if (t < 2 * K * H) {
    int u = t - K * H;
    int k = u / H, h = u % H;
    float s = 0.f;
    for (int c = 0; c < CC; ++c) s += W[(size_t)k * (H * CC) + h * CC + c] * ad_[h * CC + c];
    wad[u] = s;
  } else if (t < 2 * K * H + EDD * H) {
    int u = t - 2 * K * H;
    int d = u / H, h = u % H;
    float s = 0.f;
    for (int c = 0; c < CC; ++c) s += We[(size_t)d * (H * CC) + h * CC + c] * ae[h * CC + c];
    weae[u] = s;
  }
}

// xw = in[N,K] @ W[K,M], plus asrc/adst epilogue from the LDS tile.
template <int K, int M, int H>
__global__ __launch_bounds__(256) void k_gemm(const float* __restrict__ in, const float* __restrict__ W,
                       const float* __restrict__ was, const float* __restrict__ wad,
                       float* __restrict__ xw, float* __restrict__ asrc,
                       float* __restrict__ adst) {
  constexpr int BR = 32;
  constexpr int CG = M / 4;     // col groups of 4
  constexpr int RG = 256 / CG;  // row groups
  constexpr int R = BR / RG;    // rows per thread
  __shared__ float4 xs4[BR][K / 4];
  int tid = threadIdx.x;
  int rbase = blockIdx.x * BR;
  for (int j = tid; j < BR * K / 4; j += 256) {
    int row = j / (K / 4), kq = j % (K / 4);
    int gr = rbase + row;
    float4 v = {0.f, 0.f, 0.f, 0.f};
    if (gr < NN) v = *(const float4*)(in + (size_t)gr * K + kq * 4);
    xs4[row][kq] = v;
  }
  __syncthreads();
  int cg = tid % CG, rg = tid / CG;
  int col0 = cg * 4;
  float acc[R][4];
#pragma unroll
  for (int r = 0; r < R; ++r)
#pragma unroll
    for (int c = 0; c < 4; ++c) acc[r][c] = 0.f;
  for (int k0 = 0; k0 < K; k0 += 4) {
    float4 wv[4];
#pragma unroll
    for (int kk = 0; kk < 4; ++kk) wv[kk] = *(const float4*)(W + (size_t)(k0 + kk) * M + col0);
#pragma unroll
    for (int r = 0; r < R; ++r) {
      float4 xv = xs4[rg * R + r][k0 / 4];
      const float* xf = (const float*)&xv;
#pragma unroll
      for (int kk = 0; kk < 4; ++kk) {
        const float* wf = (const float*)&wv[kk];
        float xk = xf[kk];
#pragma unroll
        for (int c = 0; c < 4; ++c) acc[r][c] += xk * wf[c];
      }
    }
  }
#pragma unroll
  for (int r = 0; r < R; ++r) {
    int gr = rbase + rg * R + r;
    if (gr < NN) {
      float4 v;
      v.x = acc[r][0]; v.y = acc[r][1]; v.z = acc[r][2]; v.w = acc[r][3];
      *(float4*)(xw + (size_t)gr * M + col0) = v;
    }
  }
  // epilogue: asrc/adst for this row tile
  if (tid < 2 * BR * H) {
    int which = tid / (BR * H);
    int u = tid % (BR * H);
    int row = u / H, h = u % H;
    int gr = rbase + row;
    if (gr < NN) {
      const float* wv = which ? wad : was;
      const float* xr = (const float*)&xs4[row][0];
      float s = 0.f;
      for (int k = 0; k < K; ++k) s += xr[k] * wv[k * H + h];
      (which ? adst : asrc)[(size_t)gr * H + h] = s;
    }
  }
}

// logits in dst-sorted order (+ self-loop logits)
template <int H>
__global__ __launch_bounds__(256) void k_edge(const float* __restrict__ ea, const float* __restrict__ loop_ea,
                       const float* __restrict__ weae, const int* __restrict__ perm,
                       const int* __restrict__ src_sorted, const int* __restrict__ dst_sorted,
                       const float* __restrict__ asrc, const float* __restrict__ adst,
                       float* __restrict__ logit, float* __restrict__ logit_loop) {
  __shared__ float wsm[EDD * H];
  if (threadIdx.x < EDD * H) wsm[threadIdx.x] = weae[threadIdx.x];
  __syncthreads();
  int idx = blockIdx.x * blockDim.x + threadIdx.x;
  const float* row;
  int s, d;
  float* outp;
  if (idx < EE) {
    int e = perm[idx];
    row = ea + (size_t)e * EDD;
    s = src_sorted[idx];
    d = dst_sorted[idx];
    outp = logit + (size_t)idx * H;
  } else if (idx < EE + NN) {
    int n = idx - EE;
    row = loop_ea + (size_t)n * EDD;
    s = n; d = n;
    outp = logit_loop + (size_t)n * H;
  } else
    return;
  float r[EDD];
#pragma unroll
  for (int dd = 0; dd < EDD; ++dd) r[dd] = row[dd];
#pragma unroll
  for (int h = 0; h < H; ++h) {
    float ae = 0.f;
#pragma unroll
    for (int dd = 0; dd < EDD; ++dd) ae += r[dd] * wsm[dd * H + h];
    outp[h] = lrelu(asrc[(size_t)s * H + h] + adst[(size_t)d * H + h] + ae, 0.2f);
  }
}

// fused GAT node kernel: one wave per node; float4 multi-edge gather of xw.
template <int H>
__global__ __launch_bounds__(256) void k_node(const float* __restrict__ xw, const float* __restrict__ logit,
                       const float* __restrict__ logit_loop, const int* __restrict__ row_off,
                       const int* __restrict__ src_sorted, const float* __restrict__ bias,
                       float* __restrict__ out) {
  constexpr int RW4 = H * CC / 4;  // float4s per xw row
  int wid = threadIdx.x >> 6, lane = threadIdx.x & 63;
  int n = blockIdx.x * 4 + wid;
  if (n >= NN) return;
  int beg = row_off[n], end = row_off[n + 1];
  float sl[H], m[H];
#pragma unroll
  for (int h = 0; h < H; ++h) {
    sl[h] = logit_loop[(size_t)n * H + h];
    m[h] = sl[h];
  }
  // pass 1: max
  for (int i = beg + lane; i < end; i += 64) {
    const float* lv = logit + (size_t)i * H;
#pragma unroll
    for (int h = 0; h < H; ++h) m[h] = fmaxf(m[h], lv[h]);
  }
#pragma unroll
  for (int off = 32; off > 0; off >>= 1)
#pragma unroll
    for (int h = 0; h < H; ++h) m[h] = fmaxf(m[h], __shfl_xor(m[h], off));
  // pass 2: denom
  float dp[H];
#pragma unroll
  for (int h = 0; h < H; ++h) dp[h] = 0.f;
  for (int i = beg + lane; i < end; i += 64) {
    const float* lv = logit + (size_t)i * H;
#pragma unroll
    for (int h = 0; h < H; ++h) dp[h] += __expf(lv[h] - m[h]);
  }
#pragma unroll
  for (int off = 32; off > 0; off >>= 1)
#pragma unroll
    for (int h = 0; h < H; ++h) dp[h] += __shfl_xor(dp[h], off);
  float inv[H], asf[H];
#pragma unroll
  for (int h = 0; h < H; ++h) {
    float ps = __expf(sl[h] - m[h]);
    float den = dp[h] + ps;
    inv[h] = 1.f / den;
    asf[h] = ps * inv[h];
  }
  // pass 3: aggregation, alpha pre-multiplied
  const float4* xw4 = (const float4*)xw;
  float4 accA = {0.f, 0.f, 0.f, 0.f};
  float4 accB = {0.f, 0.f, 0.f, 0.f};
  for (int cb = beg; cb < end; cb += 64) {
    int i = cb + lane;
    float a[H];
    int s = 0;
    if (i < end) {
      const float* lv = logit + (size_t)i * H;
#pragma unroll
      for (int h = 0; h < H; ++h) a[h] = __expf(lv[h] - m[h]) * inv[h];
      s = src_sorted[i];
    } else {
#pragma unroll
      for (int h = 0; h < H; ++h) a[h] = 0.f;
    }
    int cnt = min(64, end - cb);
    if (H == 4) {
      int sub = lane >> 4, g = lane & 15;
      for (int j = 0; j < cnt; j += 4) {
        int jj = j + sub;
        bool valid = jj < cnt;
        int sj = __shfl(s, valid ? jj : 0);
        size_t rb = (size_t)sj * RW4 + g;
#pragma unroll
        for (int q = 0; q < 4; ++q) {
          float pj = __shfl(a[q], jj);
          pj = valid ? pj : 0.f;
          float4 v = xw4[rb + 16 * q];
          accA.x += pj * v.x; accA.y += pj * v.y; accA.z += pj * v.z; accA.w += pj * v.w;
        }
      }
    } else {
      int sub = lane >> 3, g = lane & 7;
      for (int j = 0; j < cnt; j += 8) {
        int jj = j + sub;
        bool valid = jj < cnt;
        int sj = __shfl(s, valid ? jj : 0);
        size_t rb = (size_t)sj * RW4 + g;
#pragma unroll
        for (int q = 0; q < 4; ++q) {
          float pj = __shfl(a[q >> 1], jj);
          pj = valid ? pj : 0.f;
          float4 v = xw4[rb + 8 * q];
          if (q & 1) {
            accB.x += pj * v.x; accB.y += pj * v.y; accB.z += pj * v.z; accB.w += pj * v.w;
          } else {
            accA.x += pj * v.x; accA.y += pj * v.y; accA.z += pj * v.z; accA.w += pj * v.w;
          }
        }
      }
    }
  }
  // self term (ONCE: only sub==0 lane group, since acc is reduced over subs) + reduce + store
  if (H == 4) {
    int g = lane & 15, sub = lane >> 4;
    if (sub == 0) {
      size_t rb = (size_t)n * RW4 + g;
#pragma unroll
      for (int q = 0; q < 4; ++q) {
        float4 v = xw4[rb + 16 * q];
        accA.x += asf[q] * v.x; accA.y += asf[q] * v.y; accA.z += asf[q] * v.z; accA.w += asf[q] * v.w;
      }
    }
#pragma unroll
    for (int off = 16; off < 64; off <<= 1) {
      accA.x += __shfl_xor(accA.x, off);
      accA.y += __shfl_xor(accA.y, off);
      accA.z += __shfl_xor(accA.z, off);
      accA.w += __shfl_xor(accA.w, off);
    }
    if (lane < 16) {
      float4 b4 = *(const float4*)(bias + 4 * g);
      float4 res;
      res.x = accA.x * 0.25f + b4.x;
      res.y = accA.y * 0.25f + b4.y;
      res.z = accA.z * 0.25f + b4.z;
      res.w = accA.w * 0.25f + b4.w;
      *(float4*)(out + (size_t)n * CC + 4 * g) = res;
    }
  } else {
    int g = lane & 7, sub = lane >> 3;
    if (sub == 0) {
      size_t rb = (size_t)n * RW4 + g;
#pragma unroll
      for (int q = 0; q < 4; ++q) {
        float4 v = xw4[rb + 8 * q];
        float as_ = asf[q >> 1];
        if (q & 1) {
          accB.x += as_ * v.x; accB.y += as_ * v.y; accB.z += as_ * v.z; accB.w += as_ * v.w;
        } else {
          accA.x += as_ * v.x; accA.y += as_ * v.y; accA.z += as_ * v.z; accA.w += as_ * v.w;
        }
      }
    }
#pragma unroll
    for (int off = 8; off < 64; off <<= 1) {
      accA.x += __shfl_xor(accA.x, off);
      accA.y += __shfl_xor(accA.y, off);
      accA.z += __shfl_xor(accA.z, off);
      accA.w += __shfl_xor(accA.w, off);
      accB.x += __shfl_xor(accB.x, off);
      accB.y += __shfl_xor(accB.y, off);
      accB.z += __shfl_xor(accB.z, off);
      accB.w += __shfl_xor(accB.w, off);
    }
    if (lane < 16) {
      int g2 = lane & 7;
      int c = (lane < 8) ? 4 * g2 : 32 + 4 * g2;
      float4 sv = (lane < 8) ? accA : accB;
      float4 b4 = *(const float4*)(bias + c);
      float4 res;
      res.x = sv.x * 0.5f + b4.x;
      res.y = sv.y * 0.5f + b4.y;
      res.z = sv.z * 0.5f + b4.z;
      res.w = sv.w * 0.5f + b4.w;
      *(float4*)(out + (size_t)n * CC + c) = res;
    }
  }
}

// ---------------- BatchNorm ----------------
__global__ __launch_bounds__(256) void k_bn_partial(const float* __restrict__ x, float* __restrict__ psum,
                             float* __restrict__ psum2, int rows_per_block) {
  int c = threadIdx.x & 63;
  int rsub = threadIdx.x >> 6;
  int r0 = blockIdx.x * rows_per_block;
  int r1 = min(r0 + rows_per_block, NN);
  float s = 0.f, s2 = 0.f;
  for (int r = r0 + rsub; r < r1; r += 4) {
    float v = x[(size_t)r * CC + c];
    s += v;
    s2 += v * v;
  }
  __shared__ float sm[256], sm2[256];
  sm[threadIdx.x] = s;
  sm2[threadIdx.x] = s2;
  __syncthreads();
  if (rsub == 0) {
    s = sm[c] + sm[64 + c] + sm[128 + c] + sm[192 + c];
    s2 = sm2[c] + sm2[64 + c] + sm2[128 + c] + sm2[192 + c];
    psum[blockIdx.x * CC + c] = s;
    psum2[blockIdx.x * CC + c] = s2;
  }
}

__global__ __launch_bounds__(64) void k_bn_final(const float* __restrict__ psum, const float* __restrict__ psum2,
                           const float* __restrict__ g, const float* __restrict__ be,
                           float* __restrict__ scale, float* __restrict__ shift, int nblk) {
  int c = threadIdx.x;
  if (c >= CC) return;
  float s = 0.f, s2 = 0.f;
  for (int b = 0; b < nblk; ++b) {
    s += psum[b * CC + c];
    s2 += psum2[b * CC + c];
  }
  float mu = s / (float)NN;
  float var = s2 / (float)NN - mu * mu;
  float sc = g[c] * rsqrtf(var + EPSV);
  scale[c] = sc;
  shift[c] = be[c] - mu * sc;
}

__global__ __launch_bounds__(256) void k_bn_apply(float* __restrict__ x, const float* __restrict__ scale,
                           const float* __restrict__ shift, float slope) {
  int i = blockIdx.x * blockDim.x + threadIdx.x;
  if (i >= NN * CC) return;
  int c = i & 63;
  float v = x[i] * scale[c] + shift[c];
  x[i] = lrelu(v, slope);
}

// final layer: BN + leaky_relu + pooled atomicAdd (no write-back needed)
__global__ __launch_bounds__(256) void k_bn_apply_pool(const float* __restrict__ x, const float* __restrict__ scale,
                                const float* __restrict__ shift, const int* __restrict__ batch,
                                float* __restrict__ pooled) {
  int i = blockIdx.x * blockDim.x + threadIdx.x;
  if (i >= NN * CC) return;
  int nidx = i >> 6, c = i & 63;
  float v = x[i] * scale[c] + shift[c];
  v = lrelu(v, 0.01f);
  atomicAdd(&pooled[batch[nidx] * CC + c], v);
}

__global__ __launch_bounds__(64) void k_head(const float* __restrict__ pooled, const float* __restrict__ gcnt,
                       const float* __restrict__ fw1, const float* __restrict__ fb1,
                       const float* __restrict__ fw2, const float* __restrict__ fb2,
                       float* __restrict__ out) {
  int g = blockIdx.x;
  int j = threadIdx.x;  // 64
  float inv = 1.f / fmaxf(gcnt[g], 1.f);
  float h1 = fb1[j];
  for (int k = 0; k < CC; ++k) h1 += (pooled[g * CC + k] * inv) * fw1[k * CC + j];
  h1 = fmaxf(h1, 0.f);
  float o = h1 * fw2[j];
#pragma unroll
  for (int off = 32; off > 0; off >>= 1) o += __shfl_xor(o, off);
  if (j == 0) out[g] = o + fb2[0];
}

// ---------------- launch ----------------
extern "C" void kernel_launch(void* const* d_in, const int* in_sizes, int n_in,
                              void* d_out, int out_size, void* d_ws, size_t ws_size,
                              hipStream_t stream) {
  const float* x = (const float*)d_in[0];
  const int* eidx = (const int*)d_in[1];
  const float* ea = (const float*)d_in[2];
  const int* batch = (const int*)d_in[3];
  const float* w[3] = {(const float*)d_in[4], (const float*)d_in[12], (const float*)d_in[20]};
  const float* as_[3] = {(const float*)d_in[5], (const float*)d_in[13], (const float*)d_in[21]};
  const float* ad_[3] = {(const float*)d_in[6], (const float*)d_in[14], (const float*)d_in[22]};
  const float* we_[3] = {(const float*)d_in[7], (const float*)d_in[15], (const float*)d_in[23]};
  const float* ae_[3] = {(const float*)d_in[8], (const float*)d_in[16], (const float*)d_in[24]};
  const float* b_[3] = {(const float*)d_in[9], (const float*)d_in[17], (const float*)d_in[25]};
  const float* g_[3] = {(const float*)d_in[10], (const float*)d_in[18], (const float*)d_in[26]};
  const float* be_[3] = {(const float*)d_in[11], (const float*)d_in[19], (const float*)d_in[27]};
  const float* fw1 = (const float*)d_in[28];
  const float* fb1 = (const float*)d_in[29];
  const float* fw2 = (const float*)d_in[30];
  const float* fb2 = (const float*)d_in[31];
  const int* srcp = eidx;
  const int* dstp = eidx + EE;

  char* base = (char*)d_ws;
  size_t off = 0;
  auto alloc = [&](size_t bytes) {
    void* p = base + off;
    off = (off + bytes + 255) & ~(size_t)255;
    return p;
  };
  int* deg_i = (int*)alloc((size_t)NN * 4);
  int* row_off = (int*)alloc((size_t)(NN + 1) * 4);
  int* cursor = (int*)alloc((size_t)NN * 4);
  int* perm = (int*)alloc((size_t)EE * 4);
  int* src_sorted = (int*)alloc((size_t)EE * 4);
  int* dst_sorted = (int*)alloc((size_t)EE * 4);
  float* loop_ea = (float*)alloc((size_t)NN * EDD * 4);
  float* logit = (float*)alloc((size_t)EE * 4 * 4);
  float* logit_loop = (float*)alloc((size_t)NN * 4 * 4);
  float* asrc = (float*)alloc((size_t)NN * 4 * 4);
  float* adst = (float*)alloc((size_t)NN * 4 * 4);
  float* xw = (float*)alloc((size_t)NN * 256 * 4);
  float* h0 = (float*)alloc((size_t)NN * CC * 4);
  float* h1 = (float*)alloc((size_t)NN * CC * 4);
  float* psum = (float*)alloc((size_t)128 * CC * 4);
  float* psum2 = (float*)alloc((size_t)128 * CC * 4);
  float* bnscale = (float*)alloc(CC * 4);
  float* bnshift = (float*)alloc(CC * 4);
  float* weae = (float*)alloc(EDD * 4 * 4);
  float* was = (float*)alloc((size_t)CC * 4 * 4);
  float* wad = (float*)alloc((size_t)CC * 4 * 4);
  float* pooled = (float*)alloc((size_t)GG * CC * 4);
  float* gcnt = (float*)alloc((size_t)GG * 4);
  (void)ws_size; (void)in_sizes; (void)n_in; (void)out_size;

  hipMemsetAsync(deg_i, 0, (size_t)NN * 4, stream);
  hipMemsetAsync(cursor, 0, (size_t)NN * 4, stream);
  hipMemsetAsync(pooled, 0, (size_t)GG * CC * 4, stream);
  hipMemsetAsync(gcnt, 0, (size_t)GG * 4, stream);

  k_count<<<(EE + 255) / 256, 256, 0, stream>>>(dstp, deg_i);
  k_gcnt<<<(NN + 255) / 256, 256, 0, stream>>>(batch, gcnt);
  k_scan<<<1, 1024, 0, stream>>>(deg_i, row_off);
  k_fill<<<(EE + 255) / 256, 256, 0, stream>>>(srcp, dstp, row_off, cursor, perm, src_sorted,
                                               dst_sorted);
  k_loop_ea<<<(NN + 3) / 4, 256, 0, stream>>>(ea, perm, row_off, loop_ea);

  for (int l = 0; l < 3; ++l) {
    const float* in = (l == 0) ? x : ((l == 1) ? h0 : h1);
    float* outb = (l == 0) ? h0 : ((l == 1) ? h1 : h0);
    if (l == 0) {
      k_prep<4, FIN><<<1, 1024, 0, stream>>>(w[l], as_[l], ad_[l], we_[l], ae_[l], was, wad, weae);
      k_gemm<FIN, 256, 4><<<(NN + 31) / 32, 256, 0, stream>>>(in, w[l], was, wad, xw, asrc, adst);
      k_edge<4><<<(EE + NN + 255) / 256, 256, 0, stream>>>(ea, loop_ea, weae, perm, src_sorted,
                                                           dst_sorted, asrc, adst, logit, logit_loop);
      k_node<4><<<(NN + 3) / 4, 256, 0, stream>>>(xw, logit, logit_loop, row_off, src_sorted,
                                                  b_[l], outb);
    } else if (l == 1) {
      k_prep<2, CC><<<1, 1024, 0, stream>>>(w[l], as_[l], ad_[l], we_[l], ae_[l], was, wad, weae);
      k_gemm<CC, 128, 2><<<(NN + 31) / 32, 256, 0, stream>>>(in, w[l], was, wad, xw, asrc, adst);
      k_edge<2><<<(EE + NN + 255) / 256, 256, 0, stream>>>(ea, loop_ea, weae, perm, src_sorted,
                                                           dst_sorted, asrc, adst, logit, logit_loop);
      k_node<2><<<(NN + 3) / 4, 256, 0, stream>>>(xw, logit, logit_loop, row_off, src_sorted,
                                                  b_[l], outb);
    } else {
      k_prep<4, CC><<<1, 1024, 0, stream>>>(w[l], as_[l], ad_[l], we_[l], ae_[l], was, wad, weae);
      k_gemm<CC, 256, 4><<<(NN + 31) / 32, 256, 0, stream>>>(in, w[l], was, wad, xw, asrc, adst);
      k_edge<4><<<(EE + NN + 255) / 256, 256, 0, stream>>>(ea, loop_ea, weae, perm, src_sorted,
                                                           dst_sorted, asrc, adst, logit, logit_loop);
      k_node<4><<<(NN + 3) / 4, 256, 0, stream>>>(xw, logit, logit_loop, row_off, src_sorted,
                                                  b_[l], outb);
    }

    int rpb = (NN + 127) / 128;
    k_bn_partial<<<128, 256, 0, stream>>>(outb, psum, psum2, rpb);
    k_bn_final<<<1, 64, 0, stream>>>(psum, psum2, g_[l], be_[l], bnscale, bnshift, 128);
    if (l < 2)
      k_bn_apply<<<(NN * CC + 255) / 256, 256, 0, stream>>>(outb, bnscale, bnshift, 0.0f);
    else
      k_bn_apply_pool<<<(NN * CC + 255) / 256, 256, 0, stream>>>(outb, bnscale, bnshift, batch,
                                                                 pooled);
  }

  k_head<<<GG, 64, 0, stream>>>(pooled, gcnt, fw1, fb1, fw2, fb2, (float*)d_out);
}

// Round 5
// 735.145 us; speedup vs baseline: 1.6093x; 1.2462x over previous
//
#include <hip/hip_runtime.h>
#include <cstdint>
#include <cstddef>

#define NN 50000
#define EE 800000
#define FIN 32
#define EDD 10
#define GG 512
#define CC 64
static constexpr float EPSV = 1e-5f;

typedef _Float16 h4 __attribute__((ext_vector_type(4)));

__device__ __forceinline__ float lrelu(float x, float s) { return x > 0.f ? x : s * x; }

// ---------------- preprocessing ----------------
__global__ __launch_bounds__(256) void k_count(const int* __restrict__ dst, int* __restrict__ deg) {
  int e = blockIdx.x * blockDim.x + threadIdx.x;
  if (e < EE) atomicAdd(&deg[dst[e]], 1);
}

__global__ __launch_bounds__(256) void k_gcnt(const int* __restrict__ batch, float* __restrict__ gcnt) {
  int n = blockIdx.x * blockDim.x + threadIdx.x;
  if (n < NN) atomicAdd(&gcnt[batch[n]], 1.f);
}

__global__ __launch_bounds__(1024) void k_scan(const int* __restrict__ deg, int* __restrict__ row_off) {
  __shared__ int sm[1024];
  int tid = threadIdx.x;
  constexpr int CPT = (NN + 1023) / 1024;  // 49
  int b = tid * CPT;
  int local[CPT];
  int s = 0;
#pragma unroll
  for (int j = 0; j < CPT; ++j) {
    int i = b + j;
    int v = (i < NN) ? deg[i] : 0;
    local[j] = s;
    s += v;
  }
  sm[tid] = s;
  __syncthreads();
  for (int off = 1; off < 1024; off <<= 1) {
    int t = (tid >= off) ? sm[tid - off] : 0;
    __syncthreads();
    sm[tid] += t;
    __syncthreads();
  }
  int base = (tid > 0) ? sm[tid - 1] : 0;
#pragma unroll
  for (int j = 0; j < CPT; ++j) {
    int i = b + j;
    if (i < NN) row_off[i] = base + local[j];
  }
  if (tid == 1023) row_off[NN] = sm[1023];
}

__global__ __launch_bounds__(256) void k_fill(const int* __restrict__ src, const int* __restrict__ dst,
                       const int* __restrict__ row_off, int* __restrict__ cursor,
                       int* __restrict__ perm, int* __restrict__ src_sorted) {
  int e = blockIdx.x * blockDim.x + threadIdx.x;
  if (e >= EE) return;
  int d = dst[e];
  int pos = row_off[d] + atomicAdd(&cursor[d], 1);
  perm[pos] = e;
  src_sorted[pos] = src[e];
}

// loop_ea[n][:] = mean of incoming ea rows. One wave per node.
__global__ __launch_bounds__(256) void k_loop_ea(const float* __restrict__ ea, const int* __restrict__ perm,
                          const int* __restrict__ row_off, float* __restrict__ loop_ea) {
  int wid = threadIdx.x >> 6, lane = threadIdx.x & 63;
  int n = blockIdx.x * 4 + wid;
  if (n >= NN) return;
  int beg = row_off[n], end = row_off[n + 1];
  float s[EDD];
#pragma unroll
  for (int d = 0; d < EDD; ++d) s[d] = 0.f;
  for (int i = beg + lane; i < end; i += 64) {
    const float* r = ea + (size_t)perm[i] * EDD;
#pragma unroll
    for (int d = 0; d < EDD; ++d) s[d] += r[d];
  }
#pragma unroll
  for (int off = 32; off > 0; off >>= 1)
#pragma unroll
    for (int d = 0; d < EDD; ++d) s[d] += __shfl_xor(s[d], off);
  if (lane == 0) {
    float inv = 1.f / (float)max(end - beg, 1);
#pragma unroll
    for (int d = 0; d < EDD; ++d) loop_ea[n * EDD + d] = s[d] * inv;
  }
}

// was[k*H+h] = sum_c W[k,h*C+c]*as[h,c]; wad likewise; weae[d*H+h] = sum_c We[d,h*C+c]*ae[h,c]
template <int H, int K>
__global__ __launch_bounds__(1024) void k_prep(const float* __restrict__ W, const float* __restrict__ as_,
                       const float* __restrict__ ad_, const float* __restrict__ We,
                       const float* __restrict__ ae, float* __restrict__ was,
                       float* __restrict__ wad, float* __restrict__ weae) {
  int t = threadIdx.x;
  if (t < K * H) {
    int k = t / H, h = t % H;
    float s = 0.f;
    for (int c = 0; c < CC; ++c) s += W[(size_t)k * (H * CC) + h * CC + c] * as_[h * CC + c];
    was[t] = s;
  } else if (t < 2 * K * H) {
    int u = t - K * H;
    int k = u / H, h = u % H;
    float s = 0.f;
    for (int c = 0; c < CC; ++c) s += W[(size_t)k * (H * CC) + h * CC + c] * ad_[h * CC + c];
    wad[u] = s;
  } else if (t < 2 * K * H + EDD * H) {
    int u = t - 2 * K * H;
    int d = u / H, h = u % H;
    float s = 0.f;
    for (int c = 0; c < CC; ++c) s += We[(size_t)d * (H * CC) + h * CC + c] * ae[h * CC + c];
    weae[u] = s;
  }
}

// aedge (dst-sorted) for ALL 3 layers in one pass; also self-loop rows.
__global__ __launch_bounds__(256) void k_aedge_all(
    const float* __restrict__ ea, const float* __restrict__ loop_ea, const int* __restrict__ perm,
    const float* __restrict__ weae1, const float* __restrict__ weae2, const float* __restrict__ weae3,
    float* __restrict__ ae1, float* __restrict__ ae2, float* __restrict__ ae3,
    float* __restrict__ ael1, float* __restrict__ ael2, float* __restrict__ ael3) {
  __shared__ float w1[EDD * 4], w2[EDD * 2], w3[EDD * 4];
  int t = threadIdx.x;
  if (t < EDD * 4) w1[t] = weae1[t];
  else if (t < EDD * 6) w2[t - EDD * 4] = weae2[t - EDD * 4];
  else if (t < EDD * 10) w3[t - EDD * 6] = weae3[t - EDD * 6];
  __syncthreads();
  int idx = blockIdx.x * 256 + t;
  const float* row;
  if (idx < EE) row = ea + (size_t)perm[idx] * EDD;
  else if (idx < EE + NN) row = loop_ea + (size_t)(idx - EE) * EDD;
  else return;
  float r[EDD];
#pragma unroll
  for (int d2 = 0; d2 < EDD / 2; ++d2) {
    float2 v = *(const float2*)(row + 2 * d2);
    r[2 * d2] = v.x; r[2 * d2 + 1] = v.y;
  }
  float o1[4] = {0, 0, 0, 0}, o2[2] = {0, 0}, o3[4] = {0, 0, 0, 0};
#pragma unroll
  for (int d = 0; d < EDD; ++d) {
#pragma unroll
    for (int h = 0; h < 4; ++h) o1[h] += r[d] * w1[d * 4 + h];
#pragma unroll
    for (int h = 0; h < 2; ++h) o2[h] += r[d] * w2[d * 2 + h];
#pragma unroll
    for (int h = 0; h < 4; ++h) o3[h] += r[d] * w3[d * 4 + h];
  }
  float4 v1; v1.x = o1[0]; v1.y = o1[1]; v1.z = o1[2]; v1.w = o1[3];
  float2 v2; v2.x = o2[0]; v2.y = o2[1];
  float4 v3; v3.x = o3[0]; v3.y = o3[1]; v3.z = o3[2]; v3.w = o3[3];
  if (idx < EE) {
    *(float4*)(ae1 + (size_t)idx * 4) = v1;
    *(float2*)(ae2 + (size_t)idx * 2) = v2;
    *(float4*)(ae3 + (size_t)idx * 4) = v3;
  } else {
    int n = idx - EE;
    *(float4*)(ael1 + (size_t)n * 4) = v1;
    *(float2*)(ael2 + (size_t)n * 2) = v2;
    *(float4*)(ael3 + (size_t)n * 4) = v3;
  }
}

// xw(fp16) = [BN(in)] @ W, plus asrc/adst epilogue. BN fused on the staging load.
template <int K, int M, int H, bool BN>
__global__ __launch_bounds__(256) void k_gemm(const float* __restrict__ in, const float* __restrict__ W,
                       const float* __restrict__ was, const float* __restrict__ wad,
                       const float* __restrict__ bnscale, const float* __restrict__ bnshift,
                       h4* __restrict__ xw, float* __restrict__ asrc, float* __restrict__ adst) {
  constexpr int BR = 32;
  constexpr int CG = M / 4;
  constexpr int RG = 256 / CG;
  constexpr int R = BR / RG;
  __shared__ float4 xs4[BR][K / 4];
  int tid = threadIdx.x;
  int rbase = blockIdx.x * BR;
  for (int j = tid; j < BR * K / 4; j += 256) {
    int row = j / (K / 4), kq = j % (K / 4);
    int gr = rbase + row;
    float4 v = {0.f, 0.f, 0.f, 0.f};
    if (gr < NN) v = *(const float4*)(in + (size_t)gr * K + kq * 4);
    if (BN) {
      float4 sc = *(const float4*)(bnscale + kq * 4);
      float4 sh = *(const float4*)(bnshift + kq * 4);
      v.x = fmaxf(v.x * sc.x + sh.x, 0.f);
      v.y = fmaxf(v.y * sc.y + sh.y, 0.f);
      v.z = fmaxf(v.z * sc.z + sh.z, 0.f);
      v.w = fmaxf(v.w * sc.w + sh.w, 0.f);
    }
    xs4[row][kq] = v;
  }
  __syncthreads();
  int cg = tid % CG, rg = tid / CG;
  int col0 = cg * 4;
  float acc[R][4];
#pragma unroll
  for (int r = 0; r < R; ++r)
#pragma unroll
    for (int c = 0; c < 4; ++c) acc[r][c] = 0.f;
  for (int k0 = 0; k0 < K; k0 += 4) {
    float4 wv[4];
#pragma unroll
    for (int kk = 0; kk < 4; ++kk) wv[kk] = *(const float4*)(W + (size_t)(k0 + kk) * M + col0);
#pragma unroll
    for (int r = 0; r < R; ++r) {
      float4 xv = xs4[rg * R + r][k0 / 4];
      const float* xf = (const float*)&xv;
#pragma unroll
      for (int kk = 0; kk < 4; ++kk) {
        const float* wf = (const float*)&wv[kk];
        float xk = xf[kk];
#pragma unroll
        for (int c = 0; c < 4; ++c) acc[r][c] += xk * wf[c];
      }
    }
  }
#pragma unroll
  for (int r = 0; r < R; ++r) {
    int gr = rbase + rg * R + r;
    if (gr < NN) {
      h4 hv;
      hv.x = (_Float16)acc[r][0]; hv.y = (_Float16)acc[r][1];
      hv.z = (_Float16)acc[r][2]; hv.w = (_Float16)acc[r][3];
      xw[(size_t)gr * (M / 4) + cg] = hv;
    }
  }
  if (tid < 2 * BR * H) {
    int which = tid / (BR * H);
    int u = tid % (BR * H);
    int row = u / H, h = u % H;
    int gr = rbase + row;
    if (gr < NN) {
      const float* wv = which ? wad : was;
      const float* xr = (const float*)&xs4[row][0];
      float s = 0.f;
      for (int k = 0; k < K; ++k) s += xr[k] * wv[k * H + h];
      (which ? adst : asrc)[(size_t)gr * H + h] = s;
    }
  }
}

// single-pass fused GAT node kernel: inline logits (m=0), per-head unnormalized
// accumulation, fp16 xw gather, divide by per-head denom at the end.
template <int H>
__global__ __launch_bounds__(256) void k_node(const h4* __restrict__ xw,
                       const float* __restrict__ asrc, const float* __restrict__ adst,
                       const float* __restrict__ aedge, const float* __restrict__ aedge_loop,
                       const int* __restrict__ row_off, const int* __restrict__ src_sorted,
                       const float* __restrict__ bias, float* __restrict__ out) {
  int wid = threadIdx.x >> 6, lane = threadIdx.x & 63;
  int n = blockIdx.x * 4 + wid;
  if (n >= NN) return;
  int beg = row_off[n], end = row_off[n + 1];

  if (H == 4) {
    float4 adh = *(const float4*)(adst + (size_t)n * 4);
    float4 asn = *(const float4*)(asrc + (size_t)n * 4);
    float4 ael = *(const float4*)(aedge_loop + (size_t)n * 4);
    float psv[4];
    psv[0] = __expf(lrelu(asn.x + adh.x + ael.x, 0.2f));
    psv[1] = __expf(lrelu(asn.y + adh.y + ael.y, 0.2f));
    psv[2] = __expf(lrelu(asn.z + adh.z + ael.z, 0.2f));
    psv[3] = __expf(lrelu(asn.w + adh.w + ael.w, 0.2f));
    float dp[4] = {0.f, 0.f, 0.f, 0.f};
    float4 acc[4];
#pragma unroll
    for (int q = 0; q < 4; ++q) acc[q] = make_float4(0.f, 0.f, 0.f, 0.f);
    int sub = lane >> 4, g = lane & 15;
    for (int cb = beg; cb < end; cb += 64) {
      int i = cb + lane;
      float p[4];
      int s = 0;
      if (i < end) {
        s = src_sorted[i];
        float4 ae4 = *(const float4*)(aedge + (size_t)i * 4);
        float4 as4 = *(const float4*)(asrc + (size_t)s * 4);
        p[0] = __expf(lrelu(as4.x + adh.x + ae4.x, 0.2f));
        p[1] = __expf(lrelu(as4.y + adh.y + ae4.y, 0.2f));
        p[2] = __expf(lrelu(as4.z + adh.z + ae4.z, 0.2f));
        p[3] = __expf(lrelu(as4.w + adh.w + ae4.w, 0.2f));
        dp[0] += p[0]; dp[1] += p[1]; dp[2] += p[2]; dp[3] += p[3];
      } else {
        p[0] = p[1] = p[2] = p[3] = 0.f;
      }
      int cnt = min(64, end - cb);
      for (int j = 0; j < cnt; j += 4) {
        int jj = j + sub;
        bool valid = jj < cnt;
        int sj = __shfl(s, valid ? jj : 0);
        const h4* rb = xw + (size_t)sj * 64 + g;
#pragma unroll
        for (int q = 0; q < 4; ++q) {
          float pj = __shfl(p[q], jj);
          pj = valid ? pj : 0.f;
          h4 v = rb[16 * q];
          acc[q].x += pj * (float)v.x;
          acc[q].y += pj * (float)v.y;
          acc[q].z += pj * (float)v.z;
          acc[q].w += pj * (float)v.w;
        }
      }
    }
#pragma unroll
    for (int off = 32; off > 0; off >>= 1)
#pragma unroll
      for (int q = 0; q < 4; ++q) dp[q] += __shfl_xor(dp[q], off);
    if (sub == 0) {
      const h4* rb = xw + (size_t)n * 64 + g;
#pragma unroll
      for (int q = 0; q < 4; ++q) {
        h4 v = rb[16 * q];
        acc[q].x += psv[q] * (float)v.x;
        acc[q].y += psv[q] * (float)v.y;
        acc[q].z += psv[q] * (float)v.z;
        acc[q].w += psv[q] * (float)v.w;
      }
    }
#pragma unroll
    for (int off = 16; off < 64; off <<= 1)
#pragma unroll
      for (int q = 0; q < 4; ++q) {
        acc[q].x += __shfl_xor(acc[q].x, off);
        acc[q].y += __shfl_xor(acc[q].y, off);
        acc[q].z += __shfl_xor(acc[q].z, off);
        acc[q].w += __shfl_xor(acc[q].w, off);
      }
    if (lane < 16) {
      float iv[4];
#pragma unroll
      for (int q = 0; q < 4; ++q) iv[q] = 0.25f / (dp[q] + psv[q]);
      float4 b4 = *(const float4*)(bias + 4 * g);
      float4 res;
      res.x = acc[0].x * iv[0] + acc[1].x * iv[1] + acc[2].x * iv[2] + acc[3].x * iv[3] + b4.x;
      res.y = acc[0].y * iv[0] + acc[1].y * iv[1] + acc[2].y * iv[2] + acc[3].y * iv[3] + b4.y;
      res.z = acc[0].z * iv[0] + acc[1].z * iv[1] + acc[2].z * iv[2] + acc[3].z * iv[3] + b4.z;
      res.w = acc[0].w * iv[0] + acc[1].w * iv[1] + acc[2].w * iv[2] + acc[3].w * iv[3] + b4.w;
      *(float4*)(out + (size_t)n * CC + 4 * g) = res;
    }
  } else {
    // H == 2: acc[q] = (head q>>1, channel half q&1), channels (q&1)*32 + 4g
    float2 adh = *(const float2*)(adst + (size_t)n * 2);
    float2 asn = *(const float2*)(asrc + (size_t)n * 2);
    float2 ael = *(const float2*)(aedge_loop + (size_t)n * 2);
    float psv[2];
    psv[0] = __expf(lrelu(asn.x + adh.x + ael.x, 0.2f));
    psv[1] = __expf(lrelu(asn.y + adh.y + ael.y, 0.2f));
    float dp[2] = {0.f, 0.f};
    float4 acc[4];
#pragma unroll
    for (int q = 0; q < 4; ++q) acc[q] = make_float4(0.f, 0.f, 0.f, 0.f);
    int sub = lane >> 3, g = lane & 7;
    for (int cb = beg; cb < end; cb += 64) {
      int i = cb + lane;
      float p[2];
      int s = 0;
      if (i < end) {
        s = src_sorted[i];
        float2 ae2 = *(const float2*)(aedge + (size_t)i * 2);
        float2 as2 = *(const float2*)(asrc + (size_t)s * 2);
        p[0] = __expf(lrelu(as2.x + adh.x + ae2.x, 0.2f));
        p[1] = __expf(lrelu(as2.y + adh.y + ae2.y, 0.2f));
        dp[0] += p[0]; dp[1] += p[1];
      } else {
        p[0] = p[1] = 0.f;
      }
      int cnt = min(64, end - cb);
      for (int j = 0; j < cnt; j += 8) {
        int jj = j + sub;
        bool valid = jj < cnt;
        int sj = __shfl(s, valid ? jj : 0);
        const h4* rb = xw + (size_t)sj * 32 + g;
#pragma unroll
        for (int q = 0; q < 4; ++q) {
          float pj = __shfl(p[q >> 1], jj);
          pj = valid ? pj : 0.f;
          h4 v = rb[8 * q];
          acc[q].x += pj * (float)v.x;
          acc[q].y += pj * (float)v.y;
          acc[q].z += pj * (float)v.z;
          acc[q].w += pj * (float)v.w;
        }
      }
    }
#pragma unroll
    for (int off = 32; off > 0; off >>= 1)
#pragma unroll
      for (int q = 0; q < 2; ++q) dp[q] += __shfl_xor(dp[q], off);
    if (sub == 0) {
      const h4* rb = xw + (size_t)n * 32 + g;
#pragma unroll
      for (int q = 0; q < 4; ++q) {
        h4 v = rb[8 * q];
        float ps = psv[q >> 1];
        acc[q].x += ps * (float)v.x;
        acc[q].y += ps * (float)v.y;
        acc[q].z += ps * (float)v.z;
        acc[q].w += ps * (float)v.w;
      }
    }
#pragma unroll
    for (int off = 8; off < 64; off <<= 1)
#pragma unroll
      for (int q = 0; q < 4; ++q) {
        acc[q].x += __shfl_xor(acc[q].x, off);
        acc[q].y += __shfl_xor(acc[q].y, off);
        acc[q].z += __shfl_xor(acc[q].z, off);
        acc[q].w += __shfl_xor(acc[q].w, off);
      }
    if (lane < 8) {
      float iv0 = 0.5f / (dp[0] + psv[0]);
      float iv1 = 0.5f / (dp[1] + psv[1]);
      float4 bA = *(const float4*)(bias + 4 * g);
      float4 bB = *(const float4*)(bias + 32 + 4 * g);
      float4 rA, rB;
      rA.x = acc[0].x * iv0 + acc[2].x * iv1 + bA.x;
      rA.y = acc[0].y * iv0 + acc[2].y * iv1 + bA.y;
      rA.z = acc[0].z * iv0 + acc[2].z * iv1 + bA.z;
      rA.w = acc[0].w * iv0 + acc[2].w * iv1 + bA.w;
      rB.x = acc[1].x * iv0 + acc[3].x * iv1 + bB.x;
      rB.y = acc[1].y * iv0 + acc[3].y * iv1 + bB.y;
      rB.z = acc[1].z * iv0 + acc[3].z * iv1 + bB.z;
      rB.w = acc[1].w * iv0 + acc[3].w * iv1 + bB.w;
      *(float4*)(out + (size_t)n * CC + 4 * g) = rA;
      *(float4*)(out + (size_t)n * CC + 32 + 4 * g) = rB;
    }
  }
}

// ---------------- BatchNorm ----------------
__global__ __launch_bounds__(256) void k_bn_partial(const float* __restrict__ x, float* __restrict__ psum,
                             float* __restrict__ psum2, int rows_per_block) {
  int c = threadIdx.x & 63;
  int rsub = threadIdx.x >> 6;
  int r0 = blockIdx.x * rows_per_block;
  int r1 = min(r0 + rows_per_block, NN);
  float s = 0.f, s2 = 0.f;
  for (int r = r0 + rsub; r < r1; r += 4) {
    float v = x[(size_t)r * CC + c];
    s += v;
    s2 += v * v;
  }
  __shared__ float sm[256], sm2[256];
  sm[threadIdx.x] = s;
  sm2[threadIdx.x] = s2;
  __syncthreads();
  if (rsub == 0) {
    s = sm[c] + sm[64 + c] + sm[128 + c] + sm[192 + c];
    s2 = sm2[c] + sm2[64 + c] + sm2[128 + c] + sm2[192 + c];
    psum[blockIdx.x * CC + c] = s;
    psum2[blockIdx.x * CC + c] = s2;
  }
}

__global__ __launch_bounds__(64) void k_bn_final(const float* __restrict__ psum, const float* __restrict__ psum2,
                           const float* __restrict__ g, const float* __restrict__ be,
                           float* __restrict__ scale, float* __restrict__ shift, int nblk) {
  int c = threadIdx.x;
  if (c >= CC) return;
  float s = 0.f, s2 = 0.f;
  for (int b = 0; b < nblk; ++b) {
    s += psum[b * CC + c];
    s2 += psum2[b * CC + c];
  }
  float mu = s / (float)NN;
  float var = s2 / (float)NN - mu * mu;
  float sc = g[c] * rsqrtf(var + EPSV);
  scale[c] = sc;
  shift[c] = be[c] - mu * sc;
}

// final layer: BN + leaky_relu + pooled atomicAdd
__global__ __launch_bounds__(256) void k_bn_apply_pool(const float* __restrict__ x, const float* __restrict__ scale,
                                const float* __restrict__ shift, const int* __restrict__ batch,
                                float* __restrict__ pooled) {
  int i = blockIdx.x * blockDim.x + threadIdx.x;
  if (i >= NN * CC) return;
  int nidx = i >> 6, c = i & 63;
  float v = x[i] * scale[c] + shift[c];
  v = lrelu(v, 0.01f);
  atomicAdd(&pooled[batch[nidx] * CC + c], v);
}

__global__ __launch_bounds__(64) void k_head(const float* __restrict__ pooled, const float* __restrict__ gcnt,
                       const float* __restrict__ fw1, const float* __restrict__ fb1,
                       const float* __restrict__ fw2, const float* __restrict__ fb2,
                       float* __restrict__ out) {
  int g = blockIdx.x;
  int j = threadIdx.x;
  float inv = 1.f / fmaxf(gcnt[g], 1.f);
  float h1 = fb1[j];
  for (int k = 0; k < CC; ++k) h1 += (pooled[g * CC + k] * inv) * fw1[k * CC + j];
  h1 = fmaxf(h1, 0.f);
  float o = h1 * fw2[j];
#pragma unroll
  for (int off = 32; off > 0; off >>= 1) o += __shfl_xor(o, off);
  if (j == 0) out[g] = o + fb2[0];
}

// ---------------- launch ----------------
extern "C" void kernel_launch(void* const* d_in, const int* in_sizes, int n_in,
                              void* d_out, int out_size, void* d_ws, size_t ws_size,
                              hipStream_t stream) {
  const float* x = (const float*)d_in[0];
  const int* eidx = (const int*)d_in[1];
  const float* ea = (const float*)d_in[2];
  const int* batch = (const int*)d_in[3];
  const float* w[3] = {(const float*)d_in[4], (const float*)d_in[12], (const float*)d_in[20]};
  const float* as_[3] = {(const float*)d_in[5], (const float*)d_in[13], (const float*)d_in[21]};
  const float* ad_[3] = {(const float*)d_in[6], (const float*)d_in[14], (const float*)d_in[22]};
  const float* we_[3] = {(const float*)d_in[7], (const float*)d_in[15], (const float*)d_in[23]};
  const float* ae_[3] = {(const float*)d_in[8], (const float*)d_in[16], (const float*)d_in[24]};
  const float* b_[3] = {(const float*)d_in[9], (const float*)d_in[17], (const float*)d_in[25]};
  const float* g_[3] = {(const float*)d_in[10], (const float*)d_in[18], (const float*)d_in[26]};
  const float* be_[3] = {(const float*)d_in[11], (const float*)d_in[19], (const float*)d_in[27]};
  const float* fw1 = (const float*)d_in[28];
  const float* fb1 = (const float*)d_in[29];
  const float* fw2 = (const float*)d_in[30];
  const float* fb2 = (const float*)d_in[31];
  const int* srcp = eidx;
  const int* dstp = eidx + EE;

  char* base = (char*)d_ws;
  size_t off = 0;
  auto alloc = [&](size_t bytes) {
    void* p = base + off;
    off = (off + bytes + 255) & ~(size_t)255;
    return p;
  };
  int* deg_i = (int*)alloc((size_t)NN * 4);
  int* row_off = (int*)alloc((size_t)(NN + 1) * 4);
  int* cursor = (int*)alloc((size_t)NN * 4);
  int* perm = (int*)alloc((size_t)EE * 4);
  int* src_sorted = (int*)alloc((size_t)EE * 4);
  float* loop_ea = (float*)alloc((size_t)NN * EDD * 4);
  float* ae1 = (float*)alloc((size_t)EE * 4 * 4);
  float* ae2 = (float*)alloc((size_t)EE * 2 * 4);
  float* ae3 = (float*)alloc((size_t)EE * 4 * 4);
  float* ael1 = (float*)alloc((size_t)NN * 4 * 4);
  float* ael2 = (float*)alloc((size_t)NN * 2 * 4);
  float* ael3 = (float*)alloc((size_t)NN * 4 * 4);
  float* asrc = (float*)alloc((size_t)NN * 4 * 4);
  float* adst = (float*)alloc((size_t)NN * 4 * 4);
  h4* xw16 = (h4*)alloc((size_t)NN * 256 * 2);
  float* hA = (float*)alloc((size_t)NN * CC * 4);
  float* hB = (float*)alloc((size_t)NN * CC * 4);
  float* psum = (float*)alloc((size_t)128 * CC * 4);
  float* psum2 = (float*)alloc((size_t)128 * CC * 4);
  float* bnscale = (float*)alloc(CC * 4);
  float* bnshift = (float*)alloc(CC * 4);
  float* was1 = (float*)alloc((size_t)FIN * 4 * 4);
  float* wad1 = (float*)alloc((size_t)FIN * 4 * 4);
  float* weae1 = (float*)alloc(EDD * 4 * 4);
  float* was2 = (float*)alloc((size_t)CC * 2 * 4);
  float* wad2 = (float*)alloc((size_t)CC * 2 * 4);
  float* weae2 = (float*)alloc(EDD * 2 * 4);
  float* was3 = (float*)alloc((size_t)CC * 4 * 4);
  float* wad3 = (float*)alloc((size_t)CC * 4 * 4);
  float* weae3 = (float*)alloc(EDD * 4 * 4);
  float* pooled = (float*)alloc((size_t)GG * CC * 4);
  float* gcnt = (float*)alloc((size_t)GG * 4);
  (void)ws_size; (void)in_sizes; (void)n_in; (void)out_size;

  hipMemsetAsync(deg_i, 0, (size_t)NN * 4, stream);
  hipMemsetAsync(cursor, 0, (size_t)NN * 4, stream);
  hipMemsetAsync(pooled, 0, (size_t)GG * CC * 4, stream);
  hipMemsetAsync(gcnt, 0, (size_t)GG * 4, stream);

  k_count<<<(EE + 255) / 256, 256, 0, stream>>>(dstp, deg_i);
  k_gcnt<<<(NN + 255) / 256, 256, 0, stream>>>(batch, gcnt);
  k_scan<<<1, 1024, 0, stream>>>(deg_i, row_off);
  k_fill<<<(EE + 255) / 256, 256, 0, stream>>>(srcp, dstp, row_off, cursor, perm, src_sorted);
  k_loop_ea<<<(NN + 3) / 4, 256, 0, stream>>>(ea, perm, row_off, loop_ea);
  k_prep<4, FIN><<<1, 1024, 0, stream>>>(w[0], as_[0], ad_[0], we_[0], ae_[0], was1, wad1, weae1);
  k_prep<2, CC><<<1, 1024, 0, stream>>>(w[1], as_[1], ad_[1], we_[1], ae_[1], was2, wad2, weae2);
  k_prep<4, CC><<<1, 1024, 0, stream>>>(w[2], as_[2], ad_[2], we_[2], ae_[2], was3, wad3, weae3);
  k_aedge_all<<<(EE + NN + 255) / 256, 256, 0, stream>>>(ea, loop_ea, perm, weae1, weae2, weae3,
                                                         ae1, ae2, ae3, ael1, ael2, ael3);

  // layer 1 (H=4)
  k_gemm<FIN, 256, 4, false><<<(NN + 31) / 32, 256, 0, stream>>>(x, w[0], was1, wad1, nullptr,
                                                                 nullptr, xw16, asrc, adst);
  k_node<4><<<(NN + 3) / 4, 256, 0, stream>>>(xw16, asrc, adst, ae1, ael1, row_off, src_sorted,
                                              b_[0], hA);
  k_bn_partial<<<128, 256, 0, stream>>>(hA, psum, psum2, (NN + 127) / 128);
  k_bn_final<<<1, 64, 0, stream>>>(psum, psum2, g_[0], be_[0], bnscale, bnshift, 128);

  // layer 2 (H=2), BN of layer 1 fused into GEMM staging
  k_gemm<CC, 128, 2, true><<<(NN + 31) / 32, 256, 0, stream>>>(hA, w[1], was2, wad2, bnscale,
                                                               bnshift, xw16, asrc, adst);
  k_node<2><<<(NN + 3) / 4, 256, 0, stream>>>(xw16, asrc, adst, ae2, ael2, row_off, src_sorted,
                                              b_[1], hB);
  k_bn_partial<<<128, 256, 0, stream>>>(hB, psum, psum2, (NN + 127) / 128);
  k_bn_final<<<1, 64, 0, stream>>>(psum, psum2, g_[1], be_[1], bnscale, bnshift, 128);

  // layer 3 (H=4)
  k_gemm<CC, 256, 4, true><<<(NN + 31) / 32, 256, 0, stream>>>(hB, w[2], was3, wad3, bnscale,
                                                               bnshift, xw16, asrc, adst);
  k_node<4><<<(NN + 3) / 4, 256, 0, stream>>>(xw16, asrc, adst, ae3, ael3, row_off, src_sorted,
                                              b_[2], hA);
  k_bn_partial<<<128, 256, 0, stream>>>(hA, psum, psum2, (NN + 127) / 128);
  k_bn_final<<<1, 64, 0, stream>>>(psum, psum2, g_[2], be_[2], bnscale, bnshift, 128);
  k_bn_apply_pool<<<(NN * CC + 255) / 256, 256, 0, stream>>>(hA, bnscale, bnshift, batch, pooled);

  k_head<<<GG, 64, 0, stream>>>(pooled, gcnt, fw1, fb1, fw2, fb2, (float*)d_out);
}

// Round 6
// 487.132 us; speedup vs baseline: 2.4286x; 1.5091x over previous
//
#include <hip/hip_runtime.h>
#include <cstdint>
#include <cstddef>

#define NN 50000
#define EE 800000
#define FIN 32
#define EDD 10
#define GG 512
#define CC 64
static constexpr float EPSV = 1e-5f;

typedef _Float16 h4 __attribute__((ext_vector_type(4)));

__device__ __forceinline__ float lrelu(float x, float s) { return x > 0.f ? x : s * x; }

// ---------------- preprocessing ----------------
// degree count + per-graph node count in one kernel
__global__ __launch_bounds__(256) void k_pre(const int* __restrict__ dst,
                                             const int* __restrict__ batch,
                                             int* __restrict__ deg, float* __restrict__ gcnt) {
  int e = blockIdx.x * 256 + threadIdx.x;
  if (e < EE) atomicAdd(&deg[dst[e]], 1);
  if (e < NN) atomicAdd(&gcnt[batch[e]], 1.f);
}

// single-block exclusive scan of deg[NN] -> row_off[NN+1]
__global__ __launch_bounds__(1024) void k_scan(const int* __restrict__ deg, int* __restrict__ row_off) {
  __shared__ int sm[1024];
  int tid = threadIdx.x;
  constexpr int CPT = (NN + 1023) / 1024;  // 49
  int b = tid * CPT;
  int local[CPT];
  int s = 0;
#pragma unroll
  for (int j = 0; j < CPT; ++j) {
    int i = b + j;
    int v = (i < NN) ? deg[i] : 0;
    local[j] = s;
    s += v;
  }
  sm[tid] = s;
  __syncthreads();
  for (int off = 1; off < 1024; off <<= 1) {
    int t = (tid >= off) ? sm[tid - off] : 0;
    __syncthreads();
    sm[tid] += t;
    __syncthreads();
  }
  int base = (tid > 0) ? sm[tid - 1] : 0;
#pragma unroll
  for (int j = 0; j < CPT; ++j) {
    int i = b + j;
    if (i < NN) row_off[i] = base + local[j];
  }
  if (tid == 1023) row_off[NN] = sm[1023];
}

// all 3 layers' was/wad/weae in one kernel: blockIdx = layer
__global__ __launch_bounds__(1024) void k_prep_all(
    const float* __restrict__ w1, const float* __restrict__ s1, const float* __restrict__ d1,
    const float* __restrict__ e1, const float* __restrict__ a1,
    const float* __restrict__ w2, const float* __restrict__ s2, const float* __restrict__ d2,
    const float* __restrict__ e2, const float* __restrict__ a2,
    const float* __restrict__ w3, const float* __restrict__ s3, const float* __restrict__ d3,
    const float* __restrict__ e3, const float* __restrict__ a3,
    float* __restrict__ was1, float* __restrict__ wad1, float* __restrict__ weae1,
    float* __restrict__ was2, float* __restrict__ wad2, float* __restrict__ weae2,
    float* __restrict__ was3, float* __restrict__ wad3, float* __restrict__ weae3) {
  int l = blockIdx.x;
  const float *W, *as_, *ad_, *We, *ae_;
  float *was, *wad, *weae;
  int K, H;
  if (l == 0) { W = w1; as_ = s1; ad_ = d1; We = e1; ae_ = a1; was = was1; wad = wad1; weae = weae1; K = FIN; H = 4; }
  else if (l == 1) { W = w2; as_ = s2; ad_ = d2; We = e2; ae_ = a2; was = was2; wad = wad2; weae = weae2; K = CC; H = 2; }
  else { W = w3; as_ = s3; ad_ = d3; We = e3; ae_ = a3; was = was3; wad = wad3; weae = weae3; K = CC; H = 4; }
  int M = H * CC;
  int t = threadIdx.x;
  if (t < K * H) {
    int k = t / H, h = t % H;
    float s = 0.f;
    for (int c = 0; c < CC; ++c) s += W[(size_t)k * M + h * CC + c] * as_[h * CC + c];
    was[t] = s;
  } else if (t < 2 * K * H) {
    int u = t - K * H;
    int k = u / H, h = u % H;
    float s = 0.f;
    for (int c = 0; c < CC; ++c) s += W[(size_t)k * M + h * CC + c] * ad_[h * CC + c];
    wad[u] = s;
  } else if (t < 2 * K * H + EDD * H) {
    int u = t - 2 * K * H;
    int d = u / H, h = u % H;
    float s = 0.f;
    for (int c = 0; c < CC; ++c) s += We[(size_t)d * M + h * CC + c] * ae_[h * CC + c];
    weae[u] = s;
  }
}

// CSR fill + per-edge attention terms for ALL 3 layers (scattered into dst-sorted order).
// loop_ea is not needed: self-loop aedge = segment mean of edge aedge (linearity).
__global__ __launch_bounds__(256) void k_fill(
    const int* __restrict__ src, const int* __restrict__ dst, const float* __restrict__ ea,
    const int* __restrict__ row_off, int* __restrict__ cursor,
    const float* __restrict__ weae1, const float* __restrict__ weae2,
    const float* __restrict__ weae3, int* __restrict__ src_sorted,
    float* __restrict__ ae1, float* __restrict__ ae2, float* __restrict__ ae3) {
  __shared__ float w1[EDD * 4], w2[EDD * 2], w3[EDD * 4];
  int t = threadIdx.x;
  if (t < 40) w1[t] = weae1[t];
  else if (t < 60) w2[t - 40] = weae2[t - 40];
  else if (t < 100) w3[t - 60] = weae3[t - 60];
  __syncthreads();
  int e = blockIdx.x * 256 + t;
  if (e >= EE) return;
  int d = dst[e];
  int pos = row_off[d] + atomicAdd(&cursor[d], 1);
  src_sorted[pos] = src[e];
  float r[EDD];
  const float* row = ea + (size_t)e * EDD;
#pragma unroll
  for (int i2 = 0; i2 < EDD / 2; ++i2) {
    float2 v = *(const float2*)(row + 2 * i2);
    r[2 * i2] = v.x;
    r[2 * i2 + 1] = v.y;
  }
  float o1[4] = {0, 0, 0, 0}, o2[2] = {0, 0}, o3[4] = {0, 0, 0, 0};
#pragma unroll
  for (int dd = 0; dd < EDD; ++dd) {
    float rv = r[dd];
#pragma unroll
    for (int h = 0; h < 4; ++h) o1[h] += rv * w1[dd * 4 + h];
#pragma unroll
    for (int h = 0; h < 2; ++h) o2[h] += rv * w2[dd * 2 + h];
#pragma unroll
    for (int h = 0; h < 4; ++h) o3[h] += rv * w3[dd * 4 + h];
  }
  float4 v1; v1.x = o1[0]; v1.y = o1[1]; v1.z = o1[2]; v1.w = o1[3];
  float2 v2; v2.x = o2[0]; v2.y = o2[1];
  float4 v3; v3.x = o3[0]; v3.y = o3[1]; v3.z = o3[2]; v3.w = o3[3];
  *(float4*)(ae1 + (size_t)pos * 4) = v1;
  *(float2*)(ae2 + (size_t)pos * 2) = v2;
  *(float4*)(ae3 + (size_t)pos * 4) = v3;
}

// xw(fp16) = [BN(in)] @ W, plus asrc/adst epilogue. BN fused on the staging load.
template <int K, int M, int H, bool BN>
__global__ __launch_bounds__(256) void k_gemm(const float* __restrict__ in, const float* __restrict__ W,
                       const float* __restrict__ was, const float* __restrict__ wad,
                       const float* __restrict__ bnscale, const float* __restrict__ bnshift,
                       h4* __restrict__ xw, float* __restrict__ asrc, float* __restrict__ adst) {
  constexpr int BR = 32;
  constexpr int CG = M / 4;
  constexpr int RG = 256 / CG;
  constexpr int R = BR / RG;
  __shared__ float4 xs4[BR][K / 4];
  int tid = threadIdx.x;
  int rbase = blockIdx.x * BR;
  for (int j = tid; j < BR * K / 4; j += 256) {
    int row = j / (K / 4), kq = j % (K / 4);
    int gr = rbase + row;
    float4 v = {0.f, 0.f, 0.f, 0.f};
    if (gr < NN) v = *(const float4*)(in + (size_t)gr * K + kq * 4);
    if (BN) {
      float4 sc = *(const float4*)(bnscale + kq * 4);
      float4 sh = *(const float4*)(bnshift + kq * 4);
      v.x = fmaxf(v.x * sc.x + sh.x, 0.f);
      v.y = fmaxf(v.y * sc.y + sh.y, 0.f);
      v.z = fmaxf(v.z * sc.z + sh.z, 0.f);
      v.w = fmaxf(v.w * sc.w + sh.w, 0.f);
    }
    xs4[row][kq] = v;
  }
  __syncthreads();
  int cg = tid % CG, rg = tid / CG;
  int col0 = cg * 4;
  float acc[R][4];
#pragma unroll
  for (int r = 0; r < R; ++r)
#pragma unroll
    for (int c = 0; c < 4; ++c) acc[r][c] = 0.f;
  for (int k0 = 0; k0 < K; k0 += 4) {
    float4 wv[4];
#pragma unroll
    for (int kk = 0; kk < 4; ++kk) wv[kk] = *(const float4*)(W + (size_t)(k0 + kk) * M + col0);
#pragma unroll
    for (int r = 0; r < R; ++r) {
      float4 xv = xs4[rg * R + r][k0 / 4];
      const float* xf = (const float*)&xv;
#pragma unroll
      for (int kk = 0; kk < 4; ++kk) {
        const float* wf = (const float*)&wv[kk];
        float xk = xf[kk];
#pragma unroll
        for (int c = 0; c < 4; ++c) acc[r][c] += xk * wf[c];
      }
    }
  }
#pragma unroll
  for (int r = 0; r < R; ++r) {
    int gr = rbase + rg * R + r;
    if (gr < NN) {
      h4 hv;
      hv.x = (_Float16)acc[r][0]; hv.y = (_Float16)acc[r][1];
      hv.z = (_Float16)acc[r][2]; hv.w = (_Float16)acc[r][3];
      xw[(size_t)gr * (M / 4) + cg] = hv;
    }
  }
  if (tid < 2 * BR * H) {
    int which = tid / (BR * H);
    int u = tid % (BR * H);
    int row = u / H, h = u % H;
    int gr = rbase + row;
    if (gr < NN) {
      const float* wv = which ? wad : was;
      const float* xr = (const float*)&xs4[row][0];
      float s = 0.f;
      for (int k = 0; k < K; ++k) s += xr[k] * wv[k * H + h];
      (which ? adst : asrc)[(size_t)gr * H + h] = s;
    }
  }
}

// fused GAT node kernel: 16-lane group per node (4 nodes/wave, 16/block).
// lane g owns h4 column g+16q of its node's output -> NO acc reduce.
// Self-loop logit from running aedge sum (linearity). BN stats fused (LDS + atomics).
template <int H>
__global__ __launch_bounds__(256) void k_node(const h4* __restrict__ xw,
    const float* __restrict__ asrc, const float* __restrict__ adst,
    const float* __restrict__ aedge, const int* __restrict__ row_off,
    const int* __restrict__ src_sorted, const float* __restrict__ bias,
    float* __restrict__ out, float* __restrict__ psum, float* __restrict__ psum2) {
  constexpr int SH = (H == 4) ? 6 : 5;  // log2(h4 per row)
  int lane = threadIdx.x & 63, wid = threadIdx.x >> 6;
  int grp = lane >> 4, g = lane & 15;
  int grpbase = lane & 48;
  int n = (blockIdx.x * 4 + wid) * 4 + grp;  // grid sized so n < NN always
  int beg = row_off[n], end = row_off[n + 1];
  int deg = end - beg;
  float adh[H], asn[H], dp[H], aes[H];
  float4 acc[H];
#pragma unroll
  for (int h = 0; h < H; ++h) {
    adh[h] = adst[(size_t)n * H + h];
    asn[h] = asrc[(size_t)n * H + h];
    dp[h] = 0.f; aes[h] = 0.f;
    acc[h] = make_float4(0.f, 0.f, 0.f, 0.f);
  }
  for (int cb = beg; cb < end; cb += 16) {
    int i = cb + g;
    float p[H];
    int s = 0;
    if (i < end) {
      s = src_sorted[i];
      float av[H];
      if (H == 4) {
        float4 a4 = *(const float4*)(aedge + (size_t)i * 4);
        float4 s4 = *(const float4*)(asrc + (size_t)s * 4);
        av[0] = a4.x; av[1] = a4.y; av[2] = a4.z; av[3] = a4.w;
        p[0] = __expf(lrelu(s4.x + adh[0] + av[0], 0.2f));
        p[1] = __expf(lrelu(s4.y + adh[1] + av[1], 0.2f));
        p[2] = __expf(lrelu(s4.z + adh[2] + av[2], 0.2f));
        p[3] = __expf(lrelu(s4.w + adh[3] + av[3], 0.2f));
      } else {
        float2 a2 = *(const float2*)(aedge + (size_t)i * 2);
        float2 s2 = *(const float2*)(asrc + (size_t)s * 2);
        av[0] = a2.x; av[1] = a2.y;
        p[0] = __expf(lrelu(s2.x + adh[0] + av[0], 0.2f));
        p[1] = __expf(lrelu(s2.y + adh[1] + av[1], 0.2f));
      }
#pragma unroll
      for (int h = 0; h < H; ++h) { dp[h] += p[h]; aes[h] += av[h]; }
    } else {
#pragma unroll
      for (int h = 0; h < H; ++h) p[h] = 0.f;
    }
    int cnt = min(16, end - cb);
    for (int j = 0; j < cnt; ++j) {
      int sl = grpbase | j;
      int sj = __shfl(s, sl);
      const h4* rb = xw + ((size_t)sj << SH) + g;
#pragma unroll
      for (int q = 0; q < H; ++q) {
        float pj = __shfl(p[q], sl);
        h4 v = rb[16 * q];
        acc[q].x += pj * (float)v.x;
        acc[q].y += pj * (float)v.y;
        acc[q].z += pj * (float)v.z;
        acc[q].w += pj * (float)v.w;
      }
    }
  }
  // reduce dp/aes within the 16-lane group (serves 4 nodes per instruction)
#pragma unroll
  for (int off = 1; off < 16; off <<= 1)
#pragma unroll
    for (int h = 0; h < H; ++h) {
      dp[h] += __shfl_xor(dp[h], off);
      aes[h] += __shfl_xor(aes[h], off);
    }
  float invd = 1.f / (float)max(deg, 1);
  float psv[H];
  const h4* rbs = xw + ((size_t)n << SH) + g;
#pragma unroll
  for (int q = 0; q < H; ++q) {
    psv[q] = __expf(lrelu(asn[q] + adh[q] + aes[q] * invd, 0.2f));
    h4 v = rbs[16 * q];
    acc[q].x += psv[q] * (float)v.x;
    acc[q].y += psv[q] * (float)v.y;
    acc[q].z += psv[q] * (float)v.z;
    acc[q].w += psv[q] * (float)v.w;
  }
  float4 res = *(const float4*)(bias + 4 * g);
#pragma unroll
  for (int q = 0; q < H; ++q) {
    float iv = (1.0f / H) / (dp[q] + psv[q]);
    res.x += acc[q].x * iv;
    res.y += acc[q].y * iv;
    res.z += acc[q].z * iv;
    res.w += acc[q].w * iv;
  }
  *(float4*)(out + (size_t)n * CC + 4 * g) = res;
  // fused BN statistics: block LDS reduce -> 64-slot rotated atomics
  __shared__ float sv[16][64], sq[16][64];
  int row = wid * 4 + grp;
  *(float4*)&sv[row][4 * g] = res;
  float4 r2;
  r2.x = res.x * res.x; r2.y = res.y * res.y; r2.z = res.z * res.z; r2.w = res.w * res.w;
  *(float4*)&sq[row][4 * g] = r2;
  __syncthreads();
  int tid = threadIdx.x;
  if (tid < 128) {
    int c = tid & 63, which = tid >> 6;
    const float(*m)[64] = which ? sq : sv;
    float ssum = 0.f;
#pragma unroll
    for (int r0 = 0; r0 < 16; ++r0) ssum += m[r0][c];
    atomicAdd((which ? psum2 : psum) + ((blockIdx.x & 63) * 64 + c), ssum);
  }
}

__global__ __launch_bounds__(64) void k_bn_final(const float* __restrict__ psum,
                           const float* __restrict__ psum2, const float* __restrict__ g,
                           const float* __restrict__ be, float* __restrict__ scale,
                           float* __restrict__ shift) {
  int c = threadIdx.x;
  float s = 0.f, s2 = 0.f;
  for (int b = 0; b < 64; ++b) {
    s += psum[b * 64 + c];
    s2 += psum2[b * 64 + c];
  }
  float mu = s / (float)NN;
  float var = s2 / (float)NN - mu * mu;
  float sc = g[c] * rsqrtf(var + EPSV);
  scale[c] = sc;
  shift[c] = be[c] - mu * sc;
}

// final layer: BN + leaky_relu + pooled atomicAdd
__global__ __launch_bounds__(256) void k_bn_apply_pool(const float* __restrict__ x,
                                const float* __restrict__ scale, const float* __restrict__ shift,
                                const int* __restrict__ batch, float* __restrict__ pooled) {
  int i = blockIdx.x * blockDim.x + threadIdx.x;
  if (i >= NN * CC) return;
  int nidx = i >> 6, c = i & 63;
  float v = x[i] * scale[c] + shift[c];
  v = lrelu(v, 0.01f);
  atomicAdd(&pooled[batch[nidx] * CC + c], v);
}

__global__ __launch_bounds__(64) void k_head(const float* __restrict__ pooled,
                       const float* __restrict__ gcnt,
                       const float* __restrict__ fw1, const float* __restrict__ fb1,
                       const float* __restrict__ fw2, const float* __restrict__ fb2,
                       float* __restrict__ out) {
  int g = blockIdx.x;
  int j = threadIdx.x;
  float inv = 1.f / fmaxf(gcnt[g], 1.f);
  float h1 = fb1[j];
  for (int k = 0; k < CC; ++k) h1 += (pooled[g * CC + k] * inv) * fw1[k * CC + j];
  h1 = fmaxf(h1, 0.f);
  float o = h1 * fw2[j];
#pragma unroll
  for (int off = 32; off > 0; off >>= 1) o += __shfl_xor(o, off);
  if (j == 0) out[g] = o + fb2[0];
}

// ---------------- launch ----------------
extern "C" void kernel_launch(void* const* d_in, const int* in_sizes, int n_in,
                              void* d_out, int out_size, void* d_ws, size_t ws_size,
                              hipStream_t stream) {
  const float* x = (const float*)d_in[0];
  const int* eidx = (const int*)d_in[1];
  const float* ea = (const float*)d_in[2];
  const int* batch = (const int*)d_in[3];
  const float* w[3] = {(const float*)d_in[4], (const float*)d_in[12], (const float*)d_in[20]};
  const float* as_[3] = {(const float*)d_in[5], (const float*)d_in[13], (const float*)d_in[21]};
  const float* ad_[3] = {(const float*)d_in[6], (const float*)d_in[14], (const float*)d_in[22]};
  const float* we_[3] = {(const float*)d_in[7], (const float*)d_in[15], (const float*)d_in[23]};
  const float* ae_[3] = {(const float*)d_in[8], (const float*)d_in[16], (const float*)d_in[24]};
  const float* b_[3] = {(const float*)d_in[9], (const float*)d_in[17], (const float*)d_in[25]};
  const float* g_[3] = {(const float*)d_in[10], (const float*)d_in[18], (const float*)d_in[26]};
  const float* be_[3] = {(const float*)d_in[11], (const float*)d_in[19], (const float*)d_in[27]};
  const float* fw1 = (const float*)d_in[28];
  const float* fb1 = (const float*)d_in[29];
  const float* fw2 = (const float*)d_in[30];
  const float* fb2 = (const float*)d_in[31];
  const int* srcp = eidx;
  const int* dstp = eidx + EE;

  char* base = (char*)d_ws;
  size_t off = 0;
  auto alloc = [&](size_t bytes) {
    void* p = base + off;
    off = (off + bytes + 255) & ~(size_t)255;
    return p;
  };
  // ---- zero-init region (one memset) ----
  int* deg_i = (int*)alloc((size_t)NN * 4);
  int* cursor = (int*)alloc((size_t)NN * 4);
  float* pooled = (float*)alloc((size_t)GG * CC * 4);
  float* gcnt = (float*)alloc((size_t)GG * 4);
  float* psA1 = (float*)alloc((size_t)64 * 64 * 4);
  float* psB1 = (float*)alloc((size_t)64 * 64 * 4);
  float* psA2 = (float*)alloc((size_t)64 * 64 * 4);
  float* psB2 = (float*)alloc((size_t)64 * 64 * 4);
  float* psA3 = (float*)alloc((size_t)64 * 64 * 4);
  float* psB3 = (float*)alloc((size_t)64 * 64 * 4);
  size_t zero_span = off;
  // ---- rest ----
  int* row_off = (int*)alloc((size_t)(NN + 1) * 4);
  int* src_sorted = (int*)alloc((size_t)EE * 4);
  float* ae1 = (float*)alloc((size_t)EE * 4 * 4);
  float* ae2 = (float*)alloc((size_t)EE * 2 * 4);
  float* ae3 = (float*)alloc((size_t)EE * 4 * 4);
  float* asrc = (float*)alloc((size_t)NN * 4 * 4);
  float* adst = (float*)alloc((size_t)NN * 4 * 4);
  h4* xw16 = (h4*)alloc((size_t)NN * 256 * 2);
  float* hA = (float*)alloc((size_t)NN * CC * 4);
  float* hB = (float*)alloc((size_t)NN * CC * 4);
  float* bnscale = (float*)alloc(CC * 4);
  float* bnshift = (float*)alloc(CC * 4);
  float* was1 = (float*)alloc((size_t)FIN * 4 * 4);
  float* wad1 = (float*)alloc((size_t)FIN * 4 * 4);
  float* weae1 = (float*)alloc(EDD * 4 * 4);
  float* was2 = (float*)alloc((size_t)CC * 2 * 4);
  float* wad2 = (float*)alloc((size_t)CC * 2 * 4);
  float* weae2 = (float*)alloc(EDD * 2 * 4);
  float* was3 = (float*)alloc((size_t)CC * 4 * 4);
  float* wad3 = (float*)alloc((size_t)CC * 4 * 4);
  float* weae3 = (float*)alloc(EDD * 4 * 4);
  (void)ws_size; (void)in_sizes; (void)n_in; (void)out_size;

  hipMemsetAsync(base, 0, zero_span, stream);

  k_pre<<<(EE + 255) / 256, 256, 0, stream>>>(dstp, batch, deg_i, gcnt);
  k_scan<<<1, 1024, 0, stream>>>(deg_i, row_off);
  k_prep_all<<<3, 1024, 0, stream>>>(w[0], as_[0], ad_[0], we_[0], ae_[0],
                                     w[1], as_[1], ad_[1], we_[1], ae_[1],
                                     w[2], as_[2], ad_[2], we_[2], ae_[2],
                                     was1, wad1, weae1, was2, wad2, weae2, was3, wad3, weae3);
  k_fill<<<(EE + 255) / 256, 256, 0, stream>>>(srcp, dstp, ea, row_off, cursor, weae1, weae2,
                                               weae3, src_sorted, ae1, ae2, ae3);

  // layer 1 (H=4)
  k_gemm<FIN, 256, 4, false><<<(NN + 31) / 32, 256, 0, stream>>>(x, w[0], was1, wad1, nullptr,
                                                                 nullptr, xw16, asrc, adst);
  k_node<4><<<NN / 16, 256, 0, stream>>>(xw16, asrc, adst, ae1, row_off, src_sorted, b_[0], hA,
                                         psA1, psB1);
  k_bn_final<<<1, 64, 0, stream>>>(psA1, psB1, g_[0], be_[0], bnscale, bnshift);

  // layer 2 (H=2), BN of layer 1 fused into GEMM staging
  k_gemm<CC, 128, 2, true><<<(NN + 31) / 32, 256, 0, stream>>>(hA, w[1], was2, wad2, bnscale,
                                                               bnshift, xw16, asrc, adst);
  k_node<2><<<NN / 16, 256, 0, stream>>>(xw16, asrc, adst, ae2, row_off, src_sorted, b_[1], hB,
                                         psA2, psB2);
  k_bn_final<<<1, 64, 0, stream>>>(psA2, psB2, g_[1], be_[1], bnscale, bnshift);

  // layer 3 (H=4)
  k_gemm<CC, 256, 4, true><<<(NN + 31) / 32, 256, 0, stream>>>(hB, w[2], was3, wad3, bnscale,
                                                               bnshift, xw16, asrc, adst);
  k_node<4><<<NN / 16, 256, 0, stream>>>(xw16, asrc, adst, ae3, row_off, src_sorted, b_[2], hA,
                                         psA3, psB3);
  k_bn_final<<<1, 64, 0, stream>>>(psA3, psB3, g_[2], be_[2], bnscale, bnshift);
  k_bn_apply_pool<<<(NN * CC + 255) / 256, 256, 0, stream>>>(hA, bnscale, bnshift, batch, pooled);

  k_head<<<GG, 64, 0, stream>>>(pooled, gcnt, fw1, fb1, fw2, fb2, (float*)d_out);
}